// Round 12
// baseline (229.866 us; speedup 1.0000x reference)
//
#include <hip/hip_runtime.h>
#include <math.h>

#define D_MODEL 512
#define N_HEADS 8
#define DK 64
#define QSCALE (0.0625f * 1.44269504089f)

typedef __attribute__((ext_vector_type(8))) short short8;
typedef __attribute__((ext_vector_type(4))) float f32x4;
typedef __attribute__((ext_vector_type(16))) float f32x16;

typedef __attribute__((address_space(1))) const unsigned as1_uint;
typedef __attribute__((address_space(3))) unsigned as3_uint;

__device__ __forceinline__ unsigned short f2bf(float f) {
    unsigned u = __builtin_bit_cast(unsigned, f);
    u = (u + 0x7fff + ((u >> 16) & 1)) >> 16;   // RNE
    return (unsigned short)u;
}

// ---------------- x fp32 -> bf16 ----------------
__global__ __launch_bounds__(256) void cvt_x_kernel(const float* __restrict__ x,
                                                    unsigned short* __restrict__ xb, int n8)
{
    int i = blockIdx.x * 256 + threadIdx.x;
    if (i >= n8) return;
    float4 a = ((const float4*)x)[i * 2];
    float4 b = ((const float4*)x)[i * 2 + 1];
    short8 o;
    o[0] = f2bf(a.x); o[1] = f2bf(a.y); o[2] = f2bf(a.z); o[3] = f2bf(a.w);
    o[4] = f2bf(b.x); o[5] = f2bf(b.y); o[6] = f2bf(b.z); o[7] = f2bf(b.w);
    ((short8*)xb)[i] = o;
}

// ---------------- mask fp32 {0,0.5,1} -> u8 {0,1,2} ----------------
__global__ __launch_bounds__(256) void cvt_mask_kernel(const float* __restrict__ m,
                                                       unsigned char* __restrict__ mu, int n4)
{
    int i = blockIdx.x * 256 + threadIdx.x;
    if (i >= n4) return;
    float4 v = ((const float4*)m)[i];
    uchar4 o = { (unsigned char)(v.x * 2.0f + 0.5f),
                 (unsigned char)(v.y * 2.0f + 0.5f),
                 (unsigned char)(v.z * 2.0f + 0.5f),
                 (unsigned char)(v.w * 2.0f + 0.5f) };
    ((uchar4*)mu)[i] = o;
}

// ---------------- W [K][N] fp32 -> Wt [N][K] bf16 (all 4 in one launch) ----------------
__global__ __launch_bounds__(256) void cvt_wt4_kernel(
    const float* __restrict__ Wq, const float* __restrict__ Wk,
    const float* __restrict__ Wv, const float* __restrict__ Wo,
    unsigned short* __restrict__ Wt)
{
    __shared__ float tile[64][65];
    int z = blockIdx.z;
    const float* W = (z == 0) ? Wq : (z == 1) ? Wk : (z == 2) ? Wv : Wo;
    unsigned short* dst = Wt + (size_t)z * D_MODEL * D_MODEL;
    int t = threadIdx.x;
    int c0 = blockIdx.x * 64;   // n
    int r0 = blockIdx.y * 64;   // k
    #pragma unroll
    for (int i = 0; i < 16; i++) {
        int e = i * 256 + t, r = e >> 6, c = e & 63;
        tile[c][r] = W[(size_t)(r0 + r) * D_MODEL + c0 + c];
    }
    __syncthreads();
    #pragma unroll
    for (int i = 0; i < 16; i++) {
        int e = i * 256 + t, n = e >> 6, kk = e & 63;
        dst[(size_t)(c0 + n) * D_MODEL + r0 + kk] = f2bf(tile[n][kk]);
    }
}

// ---------------- fused QKV GEMM: [q|k|v] = x @ [Wq|Wk|Wv] + b ----------------
__global__ __launch_bounds__(512) void gemm_qkv_kernel(
    const unsigned short* __restrict__ A, const unsigned short* __restrict__ Wt,
    const float* __restrict__ bq, const float* __restrict__ bk, const float* __restrict__ bv,
    unsigned short* __restrict__ qb, unsigned short* __restrict__ kb,
    unsigned short* __restrict__ vb, int M, int T)
{
    constexpr int K = D_MODEL;
    __shared__ unsigned short As[2][128 * 32];
    __shared__ unsigned short Bs[2][128 * 32];
    int t = threadIdx.x;
    int lane = t & 63, w = t >> 6;
    int ql = lane & 15, kg = lane >> 4;
    int m0 = blockIdx.y * 128, n0 = blockIdx.x * 128;
    int wm = w >> 2, wn = w & 3;
    bool vmode = (n0 >= 1024);

    const unsigned short* srcA = A + (size_t)(m0 + (t >> 2)) * K + (t & 3) * 8;
    const unsigned short* srcB = Wt + (size_t)(n0 + (t >> 2)) * K + (t & 3) * 8;

    f32x4 acc[4][2];
    #pragma unroll
    for (int i = 0; i < 4; i++)
        #pragma unroll
        for (int j = 0; j < 2; j++) { f32x4 z = {0.f, 0.f, 0.f, 0.f}; acc[i][j] = z; }

    constexpr int NIT = K / 32;
    int cur = 0;
    __builtin_amdgcn_global_load_lds((as1_uint*)(srcA),
        (as3_uint*)((char*)&As[0][0] + w * 1024), 16, 0, 0);
    __builtin_amdgcn_global_load_lds((as1_uint*)(srcB),
        (as3_uint*)((char*)&Bs[0][0] + w * 1024), 16, 0, 0);
    __syncthreads();

    for (int it = 0; it < NIT; ++it) {
        if (it + 1 < NIT) {
            int k0 = (it + 1) * 32;
            __builtin_amdgcn_global_load_lds((as1_uint*)(srcA + k0),
                (as3_uint*)((char*)&As[cur ^ 1][0] + w * 1024), 16, 0, 0);
            __builtin_amdgcn_global_load_lds((as1_uint*)(srcB + k0),
                (as3_uint*)((char*)&Bs[cur ^ 1][0] + w * 1024), 16, 0, 0);
        }
        short8 af[4], bfr[2];
        #pragma unroll
        for (int fm = 0; fm < 4; fm++)
            af[fm] = *(const short8*)((const char*)&As[cur][0] + (wm * 64 + fm * 16 + ql) * 64 + kg * 16);
        #pragma unroll
        for (int fn = 0; fn < 2; fn++)
            bfr[fn] = *(const short8*)((const char*)&Bs[cur][0] + (wn * 32 + fn * 16 + ql) * 64 + kg * 16);
        if (vmode) {
            #pragma unroll
            for (int fm = 0; fm < 4; fm++)
                #pragma unroll
                for (int fn = 0; fn < 2; fn++)
                    acc[fm][fn] = __builtin_amdgcn_mfma_f32_16x16x32_bf16(bfr[fn], af[fm], acc[fm][fn], 0, 0, 0);
        } else {
            #pragma unroll
            for (int fm = 0; fm < 4; fm++)
                #pragma unroll
                for (int fn = 0; fn < 2; fn++)
                    acc[fm][fn] = __builtin_amdgcn_mfma_f32_16x16x32_bf16(af[fm], bfr[fn], acc[fm][fn], 0, 0, 0);
        }
        __syncthreads();
        cur ^= 1;
    }

    #pragma unroll
    for (int fm = 0; fm < 4; fm++) {
        #pragma unroll
        for (int fn = 0; fn < 2; fn++) {
            if (vmode) {
                int m = m0 + wm * 64 + fm * 16 + ql;
                int b = m / T, tt = m % T;
                #pragma unroll
                for (int r = 0; r < 4; r++) {
                    int n = (n0 - 1024) + wn * 32 + fn * 16 + kg * 4 + r;
                    float val = acc[fm][fn][r] + bv[n];
                    int h = n >> 6, d = n & 63;
                    vb[((size_t)(b * N_HEADS + h) * DK + d) * T + tt] = f2bf(val);
                }
            } else {
                int n = n0 + wn * 32 + fn * 16 + ql;
                int nn = n & 511;
                bool isq = (n0 < 512);
                float bn = isq ? bq[nn] : bk[nn];
                unsigned short* dst = isq ? qb : kb;
                int h = nn >> 6, d = nn & 63;
                #pragma unroll
                for (int r = 0; r < 4; r++) {
                    int m = m0 + wm * 64 + fm * 16 + kg * 4 + r;
                    int b = m / T, tt = m % T;
                    float val = acc[fm][fn][r] + bn;
                    if (isq) val *= QSCALE;
                    dst[((size_t)(b * N_HEADS + h) * T + tt) * DK + d] = f2bf(val);
                }
            }
        }
    }
}

// ---------------- out-proj GEMM: fp32 out = attb @ Wo + bo ----------------
__global__ __launch_bounds__(512) void gemm_out_kernel(
    const unsigned short* __restrict__ A, const unsigned short* __restrict__ Bt,
    const float* __restrict__ bias, float* __restrict__ outp, int M)
{
    constexpr int K = D_MODEL;
    __shared__ unsigned short As[2][128 * 32];
    __shared__ unsigned short Bs[2][128 * 32];
    int t = threadIdx.x;
    int lane = t & 63, w = t >> 6;
    int ql = lane & 15, kg = lane >> 4;
    int m0 = blockIdx.y * 128, n0 = blockIdx.x * 128;
    int wm = w >> 2, wn = w & 3;

    const unsigned short* srcA = A + (size_t)(m0 + (t >> 2)) * K + (t & 3) * 8;
    const unsigned short* srcB = Bt + (size_t)(n0 + (t >> 2)) * K + (t & 3) * 8;

    f32x4 acc[4][2];
    #pragma unroll
    for (int i = 0; i < 4; i++)
        #pragma unroll
        for (int j = 0; j < 2; j++) { f32x4 z = {0.f, 0.f, 0.f, 0.f}; acc[i][j] = z; }

    constexpr int NIT = K / 32;
    int cur = 0;
    __builtin_amdgcn_global_load_lds((as1_uint*)(srcA),
        (as3_uint*)((char*)&As[0][0] + w * 1024), 16, 0, 0);
    __builtin_amdgcn_global_load_lds((as1_uint*)(srcB),
        (as3_uint*)((char*)&Bs[0][0] + w * 1024), 16, 0, 0);
    __syncthreads();

    for (int it = 0; it < NIT; ++it) {
        if (it + 1 < NIT) {
            int k0 = (it + 1) * 32;
            __builtin_amdgcn_global_load_lds((as1_uint*)(srcA + k0),
                (as3_uint*)((char*)&As[cur ^ 1][0] + w * 1024), 16, 0, 0);
            __builtin_amdgcn_global_load_lds((as1_uint*)(srcB + k0),
                (as3_uint*)((char*)&Bs[cur ^ 1][0] + w * 1024), 16, 0, 0);
        }
        short8 af[4], bfr[2];
        #pragma unroll
        for (int fm = 0; fm < 4; fm++)
            af[fm] = *(const short8*)((const char*)&As[cur][0] + (wm * 64 + fm * 16 + ql) * 64 + kg * 16);
        #pragma unroll
        for (int fn = 0; fn < 2; fn++)
            bfr[fn] = *(const short8*)((const char*)&Bs[cur][0] + (wn * 32 + fn * 16 + ql) * 64 + kg * 16);
        #pragma unroll
        for (int fm = 0; fm < 4; fm++)
            #pragma unroll
            for (int fn = 0; fn < 2; fn++)
                acc[fm][fn] = __builtin_amdgcn_mfma_f32_16x16x32_bf16(af[fm], bfr[fn], acc[fm][fn], 0, 0, 0);
        __syncthreads();
        cur ^= 1;
    }

    #pragma unroll
    for (int fm = 0; fm < 4; fm++) {
        #pragma unroll
        for (int fn = 0; fn < 2; fn++) {
            int n = n0 + wn * 32 + fn * 16 + ql;
            float bn = bias[n];
            #pragma unroll
            for (int r = 0; r < 4; r++) {
                int m = m0 + wm * 64 + fm * 16 + kg * 4 + r;
                outp[(size_t)m * D_MODEL + n] = acc[fm][fn][r] + bn;
            }
        }
    }
}

// ---------------- MFMA flash attention v12: in-block split-K, 8 waves ----------------
// Block = 512 thr = 8 waves; waves 0-3 (group 0) cover kv [0,T/2), waves 4-7 cover
// [T/2,T) for the SAME 128 q-rows. Grid (16, T/128) -> 2 blocks/CU = 4 waves/SIMD.
// Additive no-max softmax partials merged via one LDS round-trip (reuses Ks space).
__global__ __launch_bounds__(512, 4) void attn_mfma_kernel(
    const unsigned short* __restrict__ q, const unsigned short* __restrict__ k,
    const unsigned short* __restrict__ v, const unsigned char* __restrict__ mu,
    unsigned short* __restrict__ out, int B, int T)
{
    __shared__ unsigned short Ks[2][2][64 * 64];   // [group][buf]
    __shared__ unsigned short Vt[2][2][64 * 64];

    int t = threadIdx.x;
    int lane = t & 63, w = t >> 6;
    int wg = w & 3, g = w >> 2;          // wave-in-group, group
    int ln = lane & 31, hi = lane >> 5;
    int bh = blockIdx.x;
    int qt = blockIdx.y;
    int hh = bh & (N_HEADS - 1), b = bh >> 3;
    int qr0 = qt * 128;
    int Th = T >> 1;

    const char* kbase = (const char*)(k + (size_t)bh * T * DK) + (size_t)g * Th * 128;
    const char* vbase = (const char*)(v + (size_t)bh * DK * T);
    size_t gvofs = (size_t)g * Th * 2;

    // staging: per group, 4 waves x 64 lanes x 16B x2 = 8KB tile (K and V each)
    int lin0 = wg * 1024 + lane * 16;
    int lin1 = 4096 + lin0;
    int row0 = lin0 >> 7, row1 = lin1 >> 7;
    int sw0 = (row0 & 7) << 4, sw1 = (row1 & 7) << 4;
    const char* gK0 = kbase + (lin0 ^ sw0);
    const char* gK1 = kbase + (lin1 ^ sw1);
    const char* gV0 = vbase + (size_t)row0 * (2 * T) + gvofs + ((lin0 & 127) ^ sw0);
    const char* gV1 = vbase + (size_t)row1 * (2 * T) + gvofs + ((lin1 & 127) ^ sw1);

    // Q B-fragments: lane holds Q[q = qr0 + wg*32 + ln][ks*16 + hi*8 .. +7]
    short8 qfr[4];
    {
        const unsigned short* qrow = q + ((size_t)bh * T + qr0 + wg * 32 + ln) * DK + hi * 8;
        #pragma unroll
        for (int ks = 0; ks < 4; ks++)
            qfr[ks] = *(const short8*)(qrow + ks * 16);
    }

    // mask: lane's q-row, group's kv range
    const unsigned char* mbase = mu + (size_t)(qr0 + wg * 32 + ln) * T + (size_t)g * Th + 4 * hi;

    f32x16 oacc[2];
    #pragma unroll
    for (int db = 0; db < 2; db++)
        #pragma unroll
        for (int i = 0; i < 16; i++) oacc[db][i] = 0.f;
    float lacc = 0.f;

    // prologue: stage group's tile 0 -> buf 0
    __builtin_amdgcn_global_load_lds((as1_uint*)gK0, (as3_uint*)((char*)&Ks[g][0][0] + lin0), 16, 0, 0);
    __builtin_amdgcn_global_load_lds((as1_uint*)gK1, (as3_uint*)((char*)&Ks[g][0][0] + lin1), 16, 0, 0);
    __builtin_amdgcn_global_load_lds((as1_uint*)gV0, (as3_uint*)((char*)&Vt[g][0][0] + lin0), 16, 0, 0);
    __builtin_amdgcn_global_load_lds((as1_uint*)gV1, (as3_uint*)((char*)&Vt[g][0][0] + lin1), 16, 0, 0);

    int ntiles = Th / 64;
    for (int kt = 0; kt < ntiles; kt++) {
        __syncthreads();   // buf[cur] staged (vmcnt drained); prev reads done
        int cur = kt & 1;

        // mask for THIS tile, loaded early; TLP (4 waves/SIMD) hides latency
        unsigned mcur[8];
        {
            const unsigned char* mp = mbase + (size_t)kt * 64;
            #pragma unroll
            for (int rb = 0; rb < 2; rb++)
                #pragma unroll
                for (int gg = 0; gg < 4; gg++)
                    mcur[rb * 4 + gg] = *(const unsigned*)(mp + rb * 32 + gg * 8);
        }

        if (kt + 1 < ntiles) {
            size_t ko = (size_t)(kt + 1) * 8192;
            size_t vo = (size_t)(kt + 1) * 128;
            __builtin_amdgcn_global_load_lds((as1_uint*)(gK0 + ko),
                (as3_uint*)((char*)&Ks[g][cur ^ 1][0] + lin0), 16, 0, 0);
            __builtin_amdgcn_global_load_lds((as1_uint*)(gK1 + ko),
                (as3_uint*)((char*)&Ks[g][cur ^ 1][0] + lin1), 16, 0, 0);
            __builtin_amdgcn_global_load_lds((as1_uint*)(gV0 + vo),
                (as3_uint*)((char*)&Vt[g][cur ^ 1][0] + lin0), 16, 0, 0);
            __builtin_amdgcn_global_load_lds((as1_uint*)(gV1 + vo),
                (as3_uint*)((char*)&Vt[g][cur ^ 1][0] + lin1), 16, 0, 0);
        }

        // QK^T (swapped): sacc[rb][reg] = S[kcol = rb*32+(reg&3)+8*(reg>>2)+4*hi][q=ln]
        f32x16 sacc[2];
        #pragma unroll
        for (int rb = 0; rb < 2; rb++)
            #pragma unroll
            for (int i = 0; i < 16; i++) sacc[rb][i] = 0.f;
        __builtin_amdgcn_s_setprio(1);
        #pragma unroll
        for (int ks = 0; ks < 4; ks++) {
            #pragma unroll
            for (int rb = 0; rb < 2; rb++) {
                int row = rb * 32 + ln;
                short8 kf = *(const short8*)((const char*)&Ks[g][cur][0] +
                            ((row * 128 + ks * 32 + hi * 16) ^ ((row & 7) << 4)));
                sacc[rb] = __builtin_amdgcn_mfma_f32_32x32x16_bf16(kf, qfr[ks], sacc[rb], 0, 0, 0);
            }
        }
        __builtin_amdgcn_s_setprio(0);

        // softmax: p = exp2(s*m); PV A-frags in-register (cvt_pk + permlane32_swap)
        short8 pa[4];
        #pragma unroll
        for (int rb = 0; rb < 2; rb++) {
            float p[16];
            #pragma unroll
            for (int gg = 0; gg < 4; gg++) {
                unsigned mw = mcur[rb * 4 + gg];
                float p0 = __builtin_amdgcn_exp2f(sacc[rb][gg * 4 + 0] * (float)(mw & 0xffu));
                float p1 = __builtin_amdgcn_exp2f(sacc[rb][gg * 4 + 1] * (float)((mw >> 8) & 0xffu));
                float p2 = __builtin_amdgcn_exp2f(sacc[rb][gg * 4 + 2] * (float)((mw >> 16) & 0xffu));
                float p3 = __builtin_amdgcn_exp2f(sacc[rb][gg * 4 + 3] * (float)(mw >> 24));
                p[gg * 4 + 0] = p0; p[gg * 4 + 1] = p1; p[gg * 4 + 2] = p2; p[gg * 4 + 3] = p3;
                lacc += (p0 + p1) + (p2 + p3);
            }
            #pragma unroll
            for (int kl = 0; kl < 2; kl++) {
                int b0 = kl * 8;
                unsigned d0, d1, d2, d3;
                asm("v_cvt_pk_bf16_f32 %0, %1, %2" : "=v"(d0) : "v"(p[b0 + 0]), "v"(p[b0 + 1]));
                asm("v_cvt_pk_bf16_f32 %0, %1, %2" : "=v"(d1) : "v"(p[b0 + 2]), "v"(p[b0 + 3]));
                asm("v_cvt_pk_bf16_f32 %0, %1, %2" : "=v"(d2) : "v"(p[b0 + 4]), "v"(p[b0 + 5]));
                asm("v_cvt_pk_bf16_f32 %0, %1, %2" : "=v"(d3) : "v"(p[b0 + 6]), "v"(p[b0 + 7]));
                asm("v_permlane32_swap_b32 %0, %1" : "+v"(d0), "+v"(d2));
                asm("v_permlane32_swap_b32 %0, %1" : "+v"(d1), "+v"(d3));
                uint4 fr = { d0, d1, d2, d3 };
                pa[rb * 2 + kl] = __builtin_bit_cast(short8, fr);
            }
        }

        // PV: oacc[db] += P(32q x 64k) @ V(64k x [db*32..+31])
        __builtin_amdgcn_s_setprio(1);
        #pragma unroll
        for (int ks = 0; ks < 4; ks++) {
            #pragma unroll
            for (int db = 0; db < 2; db++) {
                int row = db * 32 + ln;
                short8 vb = *(const short8*)((const char*)&Vt[g][cur][0] +
                            ((row * 128 + ks * 32 + hi * 16) ^ ((row & 7) << 4)));
                oacc[db] = __builtin_amdgcn_mfma_f32_32x32x16_bf16(pa[ks], vb, oacc[db], 0, 0, 0);
            }
        }
        __builtin_amdgcn_s_setprio(0);
    }

    // per-lane l over this group's half
    lacc += __shfl_xor(lacc, 32, 64);

    // ---- merge group 1 partials into group 0 via LDS (reuse Ks=32KB, Vt head) ----
    __syncthreads();                       // all tiles done; LDS free to reuse
    float* Ls = (float*)&Ks[0][0][0];      // 32 x 256 floats = 32KB
    float* Ll = (float*)&Vt[0][0][0];      // 256 floats
    int sidx = wg * 64 + lane;
    if (g == 1) {
        #pragma unroll
        for (int reg = 0; reg < 16; reg++) {
            Ls[reg * 256 + sidx]        = oacc[0][reg];
            Ls[(16 + reg) * 256 + sidx] = oacc[1][reg];
        }
        Ll[sidx] = lacc;
    }
    __syncthreads();
    if (g == 0) {
        float lsum = lacc + Ll[sidx];
        #pragma unroll
        for (int reg = 0; reg < 16; reg++) {
            float o0 = oacc[0][reg] + Ls[reg * 256 + sidx];
            float o1 = oacc[1][reg] + Ls[(16 + reg) * 256 + sidx];
            int qoff = (reg & 3) + 8 * (reg >> 2) + 4 * hi;
            float linv = 1.0f / __shfl(lsum, qoff, 64);
            size_t rowo = ((size_t)b * T + qr0 + wg * 32 + qoff) * D_MODEL + hh * DK + ln;
            out[rowo]      = f2bf(o0 * linv);
            out[rowo + 32] = f2bf(o1 * linv);
        }
    }
}

extern "C" void kernel_launch(void* const* d_in, const int* in_sizes, int n_in,
                              void* d_out, int out_size, void* d_ws, size_t ws_size,
                              hipStream_t stream) {
    const float* x    = (const float*)d_in[0];
    const float* mask = (const float*)d_in[1];
    const float* Wq   = (const float*)d_in[2];
    const float* bq   = (const float*)d_in[3];
    const float* Wk   = (const float*)d_in[4];
    const float* bk   = (const float*)d_in[5];
    const float* Wv   = (const float*)d_in[6];
    const float* bv   = (const float*)d_in[7];
    const float* Wo   = (const float*)d_in[8];
    const float* bo   = (const float*)d_in[9];

    int T = (int)(sqrt((double)in_sizes[1]) + 0.5);   // 4096
    int C = D_MODEL;
    int B = in_sizes[0] / (T * C);                    // 2
    int M = B * T;

    size_t MK = (size_t)M * C;
    unsigned short* xb  = (unsigned short*)d_ws;
    unsigned short* Wtq = xb + MK;                    // [2048][512]: q,k,v,o contiguous
    unsigned short* Wto = Wtq + 3 * (size_t)C * C;
    unsigned short* qb  = Wtq + 4 * (size_t)C * C;
    unsigned short* kb  = qb + MK;
    unsigned short* vb  = kb + MK;
    unsigned short* attb = vb + MK;
    unsigned char*  mu  = (unsigned char*)(attb + MK);

    int n8 = (int)(MK / 8);
    cvt_x_kernel<<<(n8 + 255) / 256, 256, 0, stream>>>(x, xb, n8);
    int n4 = T * T / 4;
    cvt_mask_kernel<<<(n4 + 255) / 256, 256, 0, stream>>>(mask, mu, n4);
    dim3 wtg(C / 64, C / 64, 4);
    cvt_wt4_kernel<<<wtg, 256, 0, stream>>>(Wq, Wk, Wv, Wo, Wtq);

    dim3 gq(3 * C / 128, M / 128, 1);
    gemm_qkv_kernel<<<gq, 512, 0, stream>>>(xb, Wtq, bq, bk, bv, qb, kb, vb, M, T);

    dim3 ga(B * N_HEADS, T / 128, 1);
    attn_mfma_kernel<<<ga, 512, 0, stream>>>(qb, kb, vb, mu, attb, B, T);

    dim3 gg(C / 128, M / 128, 1);
    gemm_out_kernel<<<gg, 512, 0, stream>>>(attb, Wto, bo, (float*)d_out, M);
}

// Round 13
// 211.410 us; speedup vs baseline: 1.0873x; 1.0873x over previous
//
#include <hip/hip_runtime.h>
#include <math.h>

#define D_MODEL 512
#define N_HEADS 8
#define DK 64
#define QSCALE (0.0625f * 1.44269504089f)

typedef __attribute__((ext_vector_type(8))) short short8;
typedef __attribute__((ext_vector_type(4))) float f32x4;
typedef __attribute__((ext_vector_type(16))) float f32x16;

typedef __attribute__((address_space(1))) const unsigned as1_uint;
typedef __attribute__((address_space(3))) unsigned as3_uint;

__device__ __forceinline__ unsigned short f2bf(float f) {
    unsigned u = __builtin_bit_cast(unsigned, f);
    u = (u + 0x7fff + ((u >> 16) & 1)) >> 16;   // RNE
    return (unsigned short)u;
}

// ---------------- x fp32 -> bf16 ----------------
__global__ __launch_bounds__(256) void cvt_x_kernel(const float* __restrict__ x,
                                                    unsigned short* __restrict__ xb, int n8)
{
    int i = blockIdx.x * 256 + threadIdx.x;
    if (i >= n8) return;
    float4 a = ((const float4*)x)[i * 2];
    float4 b = ((const float4*)x)[i * 2 + 1];
    short8 o;
    o[0] = f2bf(a.x); o[1] = f2bf(a.y); o[2] = f2bf(a.z); o[3] = f2bf(a.w);
    o[4] = f2bf(b.x); o[5] = f2bf(b.y); o[6] = f2bf(b.z); o[7] = f2bf(b.w);
    ((short8*)xb)[i] = o;
}

// ---------------- mask fp32 {0,0.5,1} -> u8 {0,1,2} ----------------
__global__ __launch_bounds__(256) void cvt_mask_kernel(const float* __restrict__ m,
                                                       unsigned char* __restrict__ mu, int n4)
{
    int i = blockIdx.x * 256 + threadIdx.x;
    if (i >= n4) return;
    float4 v = ((const float4*)m)[i];
    uchar4 o = { (unsigned char)(v.x * 2.0f + 0.5f),
                 (unsigned char)(v.y * 2.0f + 0.5f),
                 (unsigned char)(v.z * 2.0f + 0.5f),
                 (unsigned char)(v.w * 2.0f + 0.5f) };
    ((uchar4*)mu)[i] = o;
}

// ---------------- W [K][N] fp32 -> Wt [N][K] bf16 (all 4 in one launch) ----------------
__global__ __launch_bounds__(256) void cvt_wt4_kernel(
    const float* __restrict__ Wq, const float* __restrict__ Wk,
    const float* __restrict__ Wv, const float* __restrict__ Wo,
    unsigned short* __restrict__ Wt)
{
    __shared__ float tile[64][65];
    int z = blockIdx.z;
    const float* W = (z == 0) ? Wq : (z == 1) ? Wk : (z == 2) ? Wv : Wo;
    unsigned short* dst = Wt + (size_t)z * D_MODEL * D_MODEL;
    int t = threadIdx.x;
    int c0 = blockIdx.x * 64;   // n
    int r0 = blockIdx.y * 64;   // k
    #pragma unroll
    for (int i = 0; i < 16; i++) {
        int e = i * 256 + t, r = e >> 6, c = e & 63;
        tile[c][r] = W[(size_t)(r0 + r) * D_MODEL + c0 + c];
    }
    __syncthreads();
    #pragma unroll
    for (int i = 0; i < 16; i++) {
        int e = i * 256 + t, n = e >> 6, kk = e & 63;
        dst[(size_t)(c0 + n) * D_MODEL + r0 + kk] = f2bf(tile[n][kk]);
    }
}

// ---------------- fused QKV GEMM: [q|k|v] = x @ [Wq|Wk|Wv] + b ----------------
__global__ __launch_bounds__(512) void gemm_qkv_kernel(
    const unsigned short* __restrict__ A, const unsigned short* __restrict__ Wt,
    const float* __restrict__ bq, const float* __restrict__ bk, const float* __restrict__ bv,
    unsigned short* __restrict__ qb, unsigned short* __restrict__ kb,
    unsigned short* __restrict__ vb, int M, int T)
{
    constexpr int K = D_MODEL;
    __shared__ unsigned short As[2][128 * 32];
    __shared__ unsigned short Bs[2][128 * 32];
    int t = threadIdx.x;
    int lane = t & 63, w = t >> 6;
    int ql = lane & 15, kg = lane >> 4;
    int m0 = blockIdx.y * 128, n0 = blockIdx.x * 128;
    int wm = w >> 2, wn = w & 3;
    bool vmode = (n0 >= 1024);

    const unsigned short* srcA = A + (size_t)(m0 + (t >> 2)) * K + (t & 3) * 8;
    const unsigned short* srcB = Wt + (size_t)(n0 + (t >> 2)) * K + (t & 3) * 8;

    f32x4 acc[4][2];
    #pragma unroll
    for (int i = 0; i < 4; i++)
        #pragma unroll
        for (int j = 0; j < 2; j++) { f32x4 z = {0.f, 0.f, 0.f, 0.f}; acc[i][j] = z; }

    constexpr int NIT = K / 32;
    int cur = 0;
    __builtin_amdgcn_global_load_lds((as1_uint*)(srcA),
        (as3_uint*)((char*)&As[0][0] + w * 1024), 16, 0, 0);
    __builtin_amdgcn_global_load_lds((as1_uint*)(srcB),
        (as3_uint*)((char*)&Bs[0][0] + w * 1024), 16, 0, 0);
    __syncthreads();

    for (int it = 0; it < NIT; ++it) {
        if (it + 1 < NIT) {
            int k0 = (it + 1) * 32;
            __builtin_amdgcn_global_load_lds((as1_uint*)(srcA + k0),
                (as3_uint*)((char*)&As[cur ^ 1][0] + w * 1024), 16, 0, 0);
            __builtin_amdgcn_global_load_lds((as1_uint*)(srcB + k0),
                (as3_uint*)((char*)&Bs[cur ^ 1][0] + w * 1024), 16, 0, 0);
        }
        short8 af[4], bfr[2];
        #pragma unroll
        for (int fm = 0; fm < 4; fm++)
            af[fm] = *(const short8*)((const char*)&As[cur][0] + (wm * 64 + fm * 16 + ql) * 64 + kg * 16);
        #pragma unroll
        for (int fn = 0; fn < 2; fn++)
            bfr[fn] = *(const short8*)((const char*)&Bs[cur][0] + (wn * 32 + fn * 16 + ql) * 64 + kg * 16);
        if (vmode) {
            #pragma unroll
            for (int fm = 0; fm < 4; fm++)
                #pragma unroll
                for (int fn = 0; fn < 2; fn++)
                    acc[fm][fn] = __builtin_amdgcn_mfma_f32_16x16x32_bf16(bfr[fn], af[fm], acc[fm][fn], 0, 0, 0);
        } else {
            #pragma unroll
            for (int fm = 0; fm < 4; fm++)
                #pragma unroll
                for (int fn = 0; fn < 2; fn++)
                    acc[fm][fn] = __builtin_amdgcn_mfma_f32_16x16x32_bf16(af[fm], bfr[fn], acc[fm][fn], 0, 0, 0);
        }
        __syncthreads();
        cur ^= 1;
    }

    #pragma unroll
    for (int fm = 0; fm < 4; fm++) {
        #pragma unroll
        for (int fn = 0; fn < 2; fn++) {
            if (vmode) {
                int m = m0 + wm * 64 + fm * 16 + ql;
                int b = m / T, tt = m % T;
                #pragma unroll
                for (int r = 0; r < 4; r++) {
                    int n = (n0 - 1024) + wn * 32 + fn * 16 + kg * 4 + r;
                    float val = acc[fm][fn][r] + bv[n];
                    int h = n >> 6, d = n & 63;
                    vb[((size_t)(b * N_HEADS + h) * DK + d) * T + tt] = f2bf(val);
                }
            } else {
                int n = n0 + wn * 32 + fn * 16 + ql;
                int nn = n & 511;
                bool isq = (n0 < 512);
                float bn = isq ? bq[nn] : bk[nn];
                unsigned short* dst = isq ? qb : kb;
                int h = nn >> 6, d = nn & 63;
                #pragma unroll
                for (int r = 0; r < 4; r++) {
                    int m = m0 + wm * 64 + fm * 16 + kg * 4 + r;
                    int b = m / T, tt = m % T;
                    float val = acc[fm][fn][r] + bn;
                    if (isq) val *= QSCALE;
                    dst[((size_t)(b * N_HEADS + h) * T + tt) * DK + d] = f2bf(val);
                }
            }
        }
    }
}

// ---------------- out-proj GEMM: fp32 out = attb @ Wo + bo ----------------
__global__ __launch_bounds__(512) void gemm_out_kernel(
    const unsigned short* __restrict__ A, const unsigned short* __restrict__ Bt,
    const float* __restrict__ bias, float* __restrict__ outp, int M)
{
    constexpr int K = D_MODEL;
    __shared__ unsigned short As[2][128 * 32];
    __shared__ unsigned short Bs[2][128 * 32];
    int t = threadIdx.x;
    int lane = t & 63, w = t >> 6;
    int ql = lane & 15, kg = lane >> 4;
    int m0 = blockIdx.y * 128, n0 = blockIdx.x * 128;
    int wm = w >> 2, wn = w & 3;

    const unsigned short* srcA = A + (size_t)(m0 + (t >> 2)) * K + (t & 3) * 8;
    const unsigned short* srcB = Bt + (size_t)(n0 + (t >> 2)) * K + (t & 3) * 8;

    f32x4 acc[4][2];
    #pragma unroll
    for (int i = 0; i < 4; i++)
        #pragma unroll
        for (int j = 0; j < 2; j++) { f32x4 z = {0.f, 0.f, 0.f, 0.f}; acc[i][j] = z; }

    constexpr int NIT = K / 32;
    int cur = 0;
    __builtin_amdgcn_global_load_lds((as1_uint*)(srcA),
        (as3_uint*)((char*)&As[0][0] + w * 1024), 16, 0, 0);
    __builtin_amdgcn_global_load_lds((as1_uint*)(srcB),
        (as3_uint*)((char*)&Bs[0][0] + w * 1024), 16, 0, 0);
    __syncthreads();

    for (int it = 0; it < NIT; ++it) {
        if (it + 1 < NIT) {
            int k0 = (it + 1) * 32;
            __builtin_amdgcn_global_load_lds((as1_uint*)(srcA + k0),
                (as3_uint*)((char*)&As[cur ^ 1][0] + w * 1024), 16, 0, 0);
            __builtin_amdgcn_global_load_lds((as1_uint*)(srcB + k0),
                (as3_uint*)((char*)&Bs[cur ^ 1][0] + w * 1024), 16, 0, 0);
        }
        short8 af[4], bfr[2];
        #pragma unroll
        for (int fm = 0; fm < 4; fm++)
            af[fm] = *(const short8*)((const char*)&As[cur][0] + (wm * 64 + fm * 16 + ql) * 64 + kg * 16);
        #pragma unroll
        for (int fn = 0; fn < 2; fn++)
            bfr[fn] = *(const short8*)((const char*)&Bs[cur][0] + (wn * 32 + fn * 16 + ql) * 64 + kg * 16);
        #pragma unroll
        for (int fm = 0; fm < 4; fm++)
            #pragma unroll
            for (int fn = 0; fn < 2; fn++)
                acc[fm][fn] = __builtin_amdgcn_mfma_f32_16x16x32_bf16(af[fm], bfr[fn], acc[fm][fn], 0, 0, 0);
        __syncthreads();
        cur ^= 1;
    }

    #pragma unroll
    for (int fm = 0; fm < 4; fm++) {
        #pragma unroll
        for (int fn = 0; fn < 2; fn++) {
            int n = n0 + wn * 32 + fn * 16 + ql;
            float bn = bias[n];
            #pragma unroll
            for (int r = 0; r < 4; r++) {
                int m = m0 + wm * 64 + fm * 16 + kg * 4 + r;
                outp[(size_t)m * D_MODEL + n] = acc[fm][fn][r] + bn;
            }
        }
    }
}

// ---------------- MFMA flash attention v13: R9 structure + XCD-pinned bh (T1) ----------------
// Block remap: linear n -> xcd = n&7 owns bh = xcd*2 + (s>>5), qt = s&31 (s = n>>3).
// Each XCD's L2 holds only 2 bh's K/V (2MB of 4MB) -> 31/32 K/V reads are L2 hits.
// Math/schedule identical to R9 (QB=128, 4 waves, 32x32x16, in-register P).
__global__ __launch_bounds__(256) void attn_mfma_kernel(
    const unsigned short* __restrict__ q, const unsigned short* __restrict__ k,
    const unsigned short* __restrict__ v, const unsigned char* __restrict__ mu,
    unsigned short* __restrict__ out, int B, int T)
{
    __shared__ unsigned short Ks[2][64 * 64];
    __shared__ unsigned short Vt[2][64 * 64];

    int t = threadIdx.x;
    int lane = t & 63, w = t >> 6;
    int ln = lane & 31, hi = lane >> 5;

    // XCD-aware decode of linear block id (dispatch: block i -> XCD i%8)
    int n = blockIdx.x;
    int nbh = B * N_HEADS;
    int nqt = T / 128;
    int bh, qt;
    if (nbh == 16 && nqt == 32) {
        int xcd = n & 7, s = n >> 3;
        bh = xcd * 2 + (s >> 5);
        qt = s & 31;
    } else {
        bh = n / nqt;
        qt = n % nqt;
    }
    int hh = bh & (N_HEADS - 1), b = bh >> 3;
    int qr0 = qt * 128;

    const char* kbase = (const char*)(k + (size_t)bh * T * DK);
    const char* vbase = (const char*)(v + (size_t)bh * DK * T);

    // staging addresses: LDS linear dest, inverse-swizzled global source
    int lin0 = w * 1024 + lane * 16;
    int lin1 = 4096 + lin0;
    int row0 = lin0 >> 7, row1 = lin1 >> 7;
    int sw0 = (row0 & 7) << 4, sw1 = (row1 & 7) << 4;
    const char* gK0 = kbase + (lin0 ^ sw0);
    const char* gK1 = kbase + (lin1 ^ sw1);
    const char* gV0 = vbase + (size_t)row0 * (2 * T) + ((lin0 & 127) ^ sw0);
    const char* gV1 = vbase + (size_t)row1 * (2 * T) + ((lin1 & 127) ^ sw1);

    // Q B-fragments: lane holds Q[q = qr0 + w*32 + ln][ks*16 + hi*8 .. +7]
    short8 qfr[4];
    {
        const unsigned short* qrow = q + ((size_t)bh * T + qr0 + w * 32 + ln) * DK + hi * 8;
        #pragma unroll
        for (int ks = 0; ks < 4; ks++)
            qfr[ks] = *(const short8*)(qrow + ks * 16);
    }

    // mask: lane's q-row, strided dwords (kcol = rb*32 + g*8 + 4*hi + 0..3)
    const unsigned char* mbase = mu + (size_t)(qr0 + w * 32 + ln) * T + 4 * hi;

    f32x16 oacc[2];
    #pragma unroll
    for (int db = 0; db < 2; db++)
        #pragma unroll
        for (int i = 0; i < 16; i++) oacc[db][i] = 0.f;
    float lacc = 0.f;

    // prologue: mask tile 0 + stage K/V tile 0 -> buf 0
    unsigned mcur[8];
    #pragma unroll
    for (int rb = 0; rb < 2; rb++)
        #pragma unroll
        for (int g = 0; g < 4; g++)
            mcur[rb * 4 + g] = *(const unsigned*)(mbase + rb * 32 + g * 8);
    __builtin_amdgcn_global_load_lds((as1_uint*)gK0, (as3_uint*)((char*)&Ks[0][0] + lin0), 16, 0, 0);
    __builtin_amdgcn_global_load_lds((as1_uint*)gK1, (as3_uint*)((char*)&Ks[0][0] + lin1), 16, 0, 0);
    __builtin_amdgcn_global_load_lds((as1_uint*)gV0, (as3_uint*)((char*)&Vt[0][0] + lin0), 16, 0, 0);
    __builtin_amdgcn_global_load_lds((as1_uint*)gV1, (as3_uint*)((char*)&Vt[0][0] + lin1), 16, 0, 0);

    int ntiles = T / 64;
    for (int kt = 0; kt < ntiles; kt++) {
        __syncthreads();   // buf[cur] staged (vmcnt drained); prev reads done
        int cur = kt & 1;
        bool havenext = (kt + 1) < ntiles;

        unsigned mnxt[8];
        if (havenext) {
            const unsigned char* mp = mbase + (size_t)(kt + 1) * 64;
            #pragma unroll
            for (int rb = 0; rb < 2; rb++)
                #pragma unroll
                for (int g = 0; g < 4; g++)
                    mnxt[rb * 4 + g] = *(const unsigned*)(mp + rb * 32 + g * 8);
            size_t ko = (size_t)(kt + 1) * 8192;
            size_t vo = (size_t)(kt + 1) * 128;
            __builtin_amdgcn_global_load_lds((as1_uint*)(gK0 + ko),
                (as3_uint*)((char*)&Ks[cur ^ 1][0] + lin0), 16, 0, 0);
            __builtin_amdgcn_global_load_lds((as1_uint*)(gK1 + ko),
                (as3_uint*)((char*)&Ks[cur ^ 1][0] + lin1), 16, 0, 0);
            __builtin_amdgcn_global_load_lds((as1_uint*)(gV0 + vo),
                (as3_uint*)((char*)&Vt[cur ^ 1][0] + lin0), 16, 0, 0);
            __builtin_amdgcn_global_load_lds((as1_uint*)(gV1 + vo),
                (as3_uint*)((char*)&Vt[cur ^ 1][0] + lin1), 16, 0, 0);
        }

        // QK^T (swapped): sacc[rb][reg] = S[kcol = rb*32 + (reg&3)+8*(reg>>2)+4*hi][q = ln]
        f32x16 sacc[2];
        #pragma unroll
        for (int rb = 0; rb < 2; rb++)
            #pragma unroll
            for (int i = 0; i < 16; i++) sacc[rb][i] = 0.f;
        __builtin_amdgcn_s_setprio(1);
        #pragma unroll
        for (int ks = 0; ks < 4; ks++) {
            #pragma unroll
            for (int rb = 0; rb < 2; rb++) {
                int row = rb * 32 + ln;
                short8 kf = *(const short8*)((const char*)&Ks[cur][0] +
                            ((row * 128 + ks * 32 + hi * 16) ^ ((row & 7) << 4)));
                sacc[rb] = __builtin_amdgcn_mfma_f32_32x32x16_bf16(kf, qfr[ks], sacc[rb], 0, 0, 0);
            }
        }
        __builtin_amdgcn_s_setprio(0);

        // softmax: p = exp2(s*m); build PV A-frags in-register (cvt_pk + permlane32_swap)
        short8 pa[4];
        #pragma unroll
        for (int rb = 0; rb < 2; rb++) {
            float p[16];
            #pragma unroll
            for (int g = 0; g < 4; g++) {
                unsigned mw = mcur[rb * 4 + g];
                float p0 = __builtin_amdgcn_exp2f(sacc[rb][g * 4 + 0] * (float)(mw & 0xffu));
                float p1 = __builtin_amdgcn_exp2f(sacc[rb][g * 4 + 1] * (float)((mw >> 8) & 0xffu));
                float p2 = __builtin_amdgcn_exp2f(sacc[rb][g * 4 + 2] * (float)((mw >> 16) & 0xffu));
                float p3 = __builtin_amdgcn_exp2f(sacc[rb][g * 4 + 3] * (float)(mw >> 24));
                p[g * 4 + 0] = p0; p[g * 4 + 1] = p1; p[g * 4 + 2] = p2; p[g * 4 + 3] = p3;
                lacc += (p0 + p1) + (p2 + p3);
            }
            #pragma unroll
            for (int kl = 0; kl < 2; kl++) {
                int b0 = kl * 8;
                unsigned d0, d1, d2, d3;
                asm("v_cvt_pk_bf16_f32 %0, %1, %2" : "=v"(d0) : "v"(p[b0 + 0]), "v"(p[b0 + 1]));
                asm("v_cvt_pk_bf16_f32 %0, %1, %2" : "=v"(d1) : "v"(p[b0 + 2]), "v"(p[b0 + 3]));
                asm("v_cvt_pk_bf16_f32 %0, %1, %2" : "=v"(d2) : "v"(p[b0 + 4]), "v"(p[b0 + 5]));
                asm("v_cvt_pk_bf16_f32 %0, %1, %2" : "=v"(d3) : "v"(p[b0 + 6]), "v"(p[b0 + 7]));
                asm("v_permlane32_swap_b32 %0, %1" : "+v"(d0), "+v"(d2));
                asm("v_permlane32_swap_b32 %0, %1" : "+v"(d1), "+v"(d3));
                uint4 fr = { d0, d1, d2, d3 };
                pa[rb * 2 + kl] = __builtin_bit_cast(short8, fr);
            }
        }

        // PV: oacc[db] += P(32q x 64k) @ V(64k x [db*32..+31])
        __builtin_amdgcn_s_setprio(1);
        #pragma unroll
        for (int ks = 0; ks < 4; ks++) {
            #pragma unroll
            for (int db = 0; db < 2; db++) {
                int row = db * 32 + ln;
                short8 vb = *(const short8*)((const char*)&Vt[cur][0] +
                            ((row * 128 + ks * 32 + hi * 16) ^ ((row & 7) << 4)));
                oacc[db] = __builtin_amdgcn_mfma_f32_32x32x16_bf16(pa[ks], vb, oacc[db], 0, 0, 0);
            }
        }
        __builtin_amdgcn_s_setprio(0);

        if (havenext) {
            #pragma unroll
            for (int c = 0; c < 8; c++) mcur[c] = mnxt[c];
        }
    }

    // l: lane owns q=ln; other half of kcols sits at lane^32
    lacc += __shfl_xor(lacc, 32, 64);

    // store: oacc[db][reg] is O[q = (reg&3)+8*(reg>>2)+4*hi][d = db*32 + ln]
    #pragma unroll
    for (int reg = 0; reg < 16; reg++) {
        int qoff = (reg & 3) + 8 * (reg >> 2) + 4 * hi;
        float linv = 1.0f / __shfl(lacc, qoff, 64);
        size_t rowo = ((size_t)b * T + qr0 + w * 32 + qoff) * D_MODEL + hh * DK + ln;
        out[rowo]      = f2bf(oacc[0][reg] * linv);
        out[rowo + 32] = f2bf(oacc[1][reg] * linv);
    }
}

extern "C" void kernel_launch(void* const* d_in, const int* in_sizes, int n_in,
                              void* d_out, int out_size, void* d_ws, size_t ws_size,
                              hipStream_t stream) {
    const float* x    = (const float*)d_in[0];
    const float* mask = (const float*)d_in[1];
    const float* Wq   = (const float*)d_in[2];
    const float* bq   = (const float*)d_in[3];
    const float* Wk   = (const float*)d_in[4];
    const float* bk   = (const float*)d_in[5];
    const float* Wv   = (const float*)d_in[6];
    const float* bv   = (const float*)d_in[7];
    const float* Wo   = (const float*)d_in[8];
    const float* bo   = (const float*)d_in[9];

    int T = (int)(sqrt((double)in_sizes[1]) + 0.5);   // 4096
    int C = D_MODEL;
    int B = in_sizes[0] / (T * C);                    // 2
    int M = B * T;

    size_t MK = (size_t)M * C;
    unsigned short* xb  = (unsigned short*)d_ws;
    unsigned short* Wtq = xb + MK;                    // [2048][512]: q,k,v,o contiguous
    unsigned short* Wto = Wtq + 3 * (size_t)C * C;
    unsigned short* qb  = Wtq + 4 * (size_t)C * C;
    unsigned short* kb  = qb + MK;
    unsigned short* vb  = kb + MK;
    unsigned short* attb = vb + MK;
    unsigned char*  mu  = (unsigned char*)(attb + MK);

    int n8 = (int)(MK / 8);
    cvt_x_kernel<<<(n8 + 255) / 256, 256, 0, stream>>>(x, xb, n8);
    int n4 = T * T / 4;
    cvt_mask_kernel<<<(n4 + 255) / 256, 256, 0, stream>>>(mask, mu, n4);
    dim3 wtg(C / 64, C / 64, 4);
    cvt_wt4_kernel<<<wtg, 256, 0, stream>>>(Wq, Wk, Wv, Wo, Wtq);

    dim3 gq(3 * C / 128, M / 128, 1);
    gemm_qkv_kernel<<<gq, 512, 0, stream>>>(xb, Wtq, bq, bk, bv, qb, kb, vb, M, T);

    int nblocks = (B * N_HEADS) * (T / 128);
    attn_mfma_kernel<<<nblocks, 256, 0, stream>>>(qb, kb, vb, mu, attb, B, T);

    dim3 gg(C / 128, M / 128, 1);
    gemm_out_kernel<<<gg, 512, 0, stream>>>(attb, Wto, bo, (float*)d_out, M);
}

// Round 14
// 208.739 us; speedup vs baseline: 1.1012x; 1.0128x over previous
//
#include <hip/hip_runtime.h>
#include <math.h>

#define D_MODEL 512
#define N_HEADS 8
#define DK 64
#define QSCALE (0.0625f * 1.44269504089f)

typedef __attribute__((ext_vector_type(8))) short short8;
typedef __attribute__((ext_vector_type(4))) float f32x4;
typedef __attribute__((ext_vector_type(16))) float f32x16;

typedef __attribute__((address_space(1))) const unsigned as1_uint;
typedef __attribute__((address_space(3))) unsigned as3_uint;

__device__ __forceinline__ unsigned short f2bf(float f) {
    unsigned u = __builtin_bit_cast(unsigned, f);
    u = (u + 0x7fff + ((u >> 16) & 1)) >> 16;   // RNE
    return (unsigned short)u;
}

// ---------------- x fp32 -> bf16 ----------------
__global__ __launch_bounds__(256) void cvt_x_kernel(const float* __restrict__ x,
                                                    unsigned short* __restrict__ xb, int n8)
{
    int i = blockIdx.x * 256 + threadIdx.x;
    if (i >= n8) return;
    float4 a = ((const float4*)x)[i * 2];
    float4 b = ((const float4*)x)[i * 2 + 1];
    short8 o;
    o[0] = f2bf(a.x); o[1] = f2bf(a.y); o[2] = f2bf(a.z); o[3] = f2bf(a.w);
    o[4] = f2bf(b.x); o[5] = f2bf(b.y); o[6] = f2bf(b.z); o[7] = f2bf(b.w);
    ((short8*)xb)[i] = o;
}

// ---------------- mask fp32 {0,0.5,1} -> u8 {0,1,2} ----------------
__global__ __launch_bounds__(256) void cvt_mask_kernel(const float* __restrict__ m,
                                                       unsigned char* __restrict__ mu, int n4)
{
    int i = blockIdx.x * 256 + threadIdx.x;
    if (i >= n4) return;
    float4 v = ((const float4*)m)[i];
    uchar4 o = { (unsigned char)(v.x * 2.0f + 0.5f),
                 (unsigned char)(v.y * 2.0f + 0.5f),
                 (unsigned char)(v.z * 2.0f + 0.5f),
                 (unsigned char)(v.w * 2.0f + 0.5f) };
    ((uchar4*)mu)[i] = o;
}

// ---------------- W [K][N] fp32 -> Wt [N][K] bf16 (all 4 in one launch) ----------------
__global__ __launch_bounds__(256) void cvt_wt4_kernel(
    const float* __restrict__ Wq, const float* __restrict__ Wk,
    const float* __restrict__ Wv, const float* __restrict__ Wo,
    unsigned short* __restrict__ Wt)
{
    __shared__ float tile[64][65];
    int z = blockIdx.z;
    const float* W = (z == 0) ? Wq : (z == 1) ? Wk : (z == 2) ? Wv : Wo;
    unsigned short* dst = Wt + (size_t)z * D_MODEL * D_MODEL;
    int t = threadIdx.x;
    int c0 = blockIdx.x * 64;   // n
    int r0 = blockIdx.y * 64;   // k
    #pragma unroll
    for (int i = 0; i < 16; i++) {
        int e = i * 256 + t, r = e >> 6, c = e & 63;
        tile[c][r] = W[(size_t)(r0 + r) * D_MODEL + c0 + c];
    }
    __syncthreads();
    #pragma unroll
    for (int i = 0; i < 16; i++) {
        int e = i * 256 + t, n = e >> 6, kk = e & 63;
        dst[(size_t)(c0 + n) * D_MODEL + r0 + kk] = f2bf(tile[n][kk]);
    }
}

// ---------------- fused QKV GEMM: [q|k|v] = x @ [Wq|Wk|Wv] + b ----------------
__global__ __launch_bounds__(512) void gemm_qkv_kernel(
    const unsigned short* __restrict__ A, const unsigned short* __restrict__ Wt,
    const float* __restrict__ bq, const float* __restrict__ bk, const float* __restrict__ bv,
    unsigned short* __restrict__ qb, unsigned short* __restrict__ kb,
    unsigned short* __restrict__ vb, int M, int T)
{
    constexpr int K = D_MODEL;
    __shared__ unsigned short As[2][128 * 32];
    __shared__ unsigned short Bs[2][128 * 32];
    int t = threadIdx.x;
    int lane = t & 63, w = t >> 6;
    int ql = lane & 15, kg = lane >> 4;
    int m0 = blockIdx.y * 128, n0 = blockIdx.x * 128;
    int wm = w >> 2, wn = w & 3;
    bool vmode = (n0 >= 1024);

    const unsigned short* srcA = A + (size_t)(m0 + (t >> 2)) * K + (t & 3) * 8;
    const unsigned short* srcB = Wt + (size_t)(n0 + (t >> 2)) * K + (t & 3) * 8;

    f32x4 acc[4][2];
    #pragma unroll
    for (int i = 0; i < 4; i++)
        #pragma unroll
        for (int j = 0; j < 2; j++) { f32x4 z = {0.f, 0.f, 0.f, 0.f}; acc[i][j] = z; }

    constexpr int NIT = K / 32;
    int cur = 0;
    __builtin_amdgcn_global_load_lds((as1_uint*)(srcA),
        (as3_uint*)((char*)&As[0][0] + w * 1024), 16, 0, 0);
    __builtin_amdgcn_global_load_lds((as1_uint*)(srcB),
        (as3_uint*)((char*)&Bs[0][0] + w * 1024), 16, 0, 0);
    __syncthreads();

    for (int it = 0; it < NIT; ++it) {
        if (it + 1 < NIT) {
            int k0 = (it + 1) * 32;
            __builtin_amdgcn_global_load_lds((as1_uint*)(srcA + k0),
                (as3_uint*)((char*)&As[cur ^ 1][0] + w * 1024), 16, 0, 0);
            __builtin_amdgcn_global_load_lds((as1_uint*)(srcB + k0),
                (as3_uint*)((char*)&Bs[cur ^ 1][0] + w * 1024), 16, 0, 0);
        }
        short8 af[4], bfr[2];
        #pragma unroll
        for (int fm = 0; fm < 4; fm++)
            af[fm] = *(const short8*)((const char*)&As[cur][0] + (wm * 64 + fm * 16 + ql) * 64 + kg * 16);
        #pragma unroll
        for (int fn = 0; fn < 2; fn++)
            bfr[fn] = *(const short8*)((const char*)&Bs[cur][0] + (wn * 32 + fn * 16 + ql) * 64 + kg * 16);
        if (vmode) {
            #pragma unroll
            for (int fm = 0; fm < 4; fm++)
                #pragma unroll
                for (int fn = 0; fn < 2; fn++)
                    acc[fm][fn] = __builtin_amdgcn_mfma_f32_16x16x32_bf16(bfr[fn], af[fm], acc[fm][fn], 0, 0, 0);
        } else {
            #pragma unroll
            for (int fm = 0; fm < 4; fm++)
                #pragma unroll
                for (int fn = 0; fn < 2; fn++)
                    acc[fm][fn] = __builtin_amdgcn_mfma_f32_16x16x32_bf16(af[fm], bfr[fn], acc[fm][fn], 0, 0, 0);
        }
        __syncthreads();
        cur ^= 1;
    }

    #pragma unroll
    for (int fm = 0; fm < 4; fm++) {
        #pragma unroll
        for (int fn = 0; fn < 2; fn++) {
            if (vmode) {
                int m = m0 + wm * 64 + fm * 16 + ql;
                int b = m / T, tt = m % T;
                #pragma unroll
                for (int r = 0; r < 4; r++) {
                    int n = (n0 - 1024) + wn * 32 + fn * 16 + kg * 4 + r;
                    float val = acc[fm][fn][r] + bv[n];
                    int h = n >> 6, d = n & 63;
                    vb[((size_t)(b * N_HEADS + h) * DK + d) * T + tt] = f2bf(val);
                }
            } else {
                int n = n0 + wn * 32 + fn * 16 + ql;
                int nn = n & 511;
                bool isq = (n0 < 512);
                float bn = isq ? bq[nn] : bk[nn];
                unsigned short* dst = isq ? qb : kb;
                int h = nn >> 6, d = nn & 63;
                #pragma unroll
                for (int r = 0; r < 4; r++) {
                    int m = m0 + wm * 64 + fm * 16 + kg * 4 + r;
                    int b = m / T, tt = m % T;
                    float val = acc[fm][fn][r] + bn;
                    if (isq) val *= QSCALE;
                    dst[((size_t)(b * N_HEADS + h) * T + tt) * DK + d] = f2bf(val);
                }
            }
        }
    }
}

// ---------------- out-proj GEMM: fp32 out = attb @ Wo + bo ----------------
__global__ __launch_bounds__(512) void gemm_out_kernel(
    const unsigned short* __restrict__ A, const unsigned short* __restrict__ Bt,
    const float* __restrict__ bias, float* __restrict__ outp, int M)
{
    constexpr int K = D_MODEL;
    __shared__ unsigned short As[2][128 * 32];
    __shared__ unsigned short Bs[2][128 * 32];
    int t = threadIdx.x;
    int lane = t & 63, w = t >> 6;
    int ql = lane & 15, kg = lane >> 4;
    int m0 = blockIdx.y * 128, n0 = blockIdx.x * 128;
    int wm = w >> 2, wn = w & 3;

    const unsigned short* srcA = A + (size_t)(m0 + (t >> 2)) * K + (t & 3) * 8;
    const unsigned short* srcB = Bt + (size_t)(n0 + (t >> 2)) * K + (t & 3) * 8;

    f32x4 acc[4][2];
    #pragma unroll
    for (int i = 0; i < 4; i++)
        #pragma unroll
        for (int j = 0; j < 2; j++) { f32x4 z = {0.f, 0.f, 0.f, 0.f}; acc[i][j] = z; }

    constexpr int NIT = K / 32;
    int cur = 0;
    __builtin_amdgcn_global_load_lds((as1_uint*)(srcA),
        (as3_uint*)((char*)&As[0][0] + w * 1024), 16, 0, 0);
    __builtin_amdgcn_global_load_lds((as1_uint*)(srcB),
        (as3_uint*)((char*)&Bs[0][0] + w * 1024), 16, 0, 0);
    __syncthreads();

    for (int it = 0; it < NIT; ++it) {
        if (it + 1 < NIT) {
            int k0 = (it + 1) * 32;
            __builtin_amdgcn_global_load_lds((as1_uint*)(srcA + k0),
                (as3_uint*)((char*)&As[cur ^ 1][0] + w * 1024), 16, 0, 0);
            __builtin_amdgcn_global_load_lds((as1_uint*)(srcB + k0),
                (as3_uint*)((char*)&Bs[cur ^ 1][0] + w * 1024), 16, 0, 0);
        }
        short8 af[4], bfr[2];
        #pragma unroll
        for (int fm = 0; fm < 4; fm++)
            af[fm] = *(const short8*)((const char*)&As[cur][0] + (wm * 64 + fm * 16 + ql) * 64 + kg * 16);
        #pragma unroll
        for (int fn = 0; fn < 2; fn++)
            bfr[fn] = *(const short8*)((const char*)&Bs[cur][0] + (wn * 32 + fn * 16 + ql) * 64 + kg * 16);
        #pragma unroll
        for (int fm = 0; fm < 4; fm++)
            #pragma unroll
            for (int fn = 0; fn < 2; fn++)
                acc[fm][fn] = __builtin_amdgcn_mfma_f32_16x16x32_bf16(af[fm], bfr[fn], acc[fm][fn], 0, 0, 0);
        __syncthreads();
        cur ^= 1;
    }

    #pragma unroll
    for (int fm = 0; fm < 4; fm++) {
        #pragma unroll
        for (int fn = 0; fn < 2; fn++) {
            int n = n0 + wn * 32 + fn * 16 + ql;
            float bn = bias[n];
            #pragma unroll
            for (int r = 0; r < 4; r++) {
                int m = m0 + wm * 64 + fm * 16 + kg * 4 + r;
                outp[(size_t)m * D_MODEL + n] = acc[fm][fn][r] + bn;
            }
        }
    }
}

// ---------------- MFMA flash attention v14: pipelined PV(t-1) + MFMA-computed l ----------------
// R13 base (QB=128, 4 waves, 32x32x16, in-reg P, XCD-pinned bh) with:
//  - pa carried one tile: iteration t issues QK(t) then PV(t-1) (independent) so the
//    matrix pipe covers QK's latency and softmax(t) drains in PV's shadow. V triple-buffered.
//  - l computed by 4 ones-column MFMAs per tile -> same reg layout as oacc, shfl-free divide.
__global__ __launch_bounds__(256) void attn_mfma_kernel(
    const unsigned short* __restrict__ q, const unsigned short* __restrict__ k,
    const unsigned short* __restrict__ v, const unsigned char* __restrict__ mu,
    unsigned short* __restrict__ out, int B, int T)
{
    __shared__ unsigned short Ks[2][64 * 64];
    __shared__ unsigned short Vt[3][64 * 64];

    int t = threadIdx.x;
    int lane = t & 63, w = t >> 6;
    int ln = lane & 31, hi = lane >> 5;

    // XCD-aware decode of linear block id (dispatch: block i -> XCD i%8)
    int n = blockIdx.x;
    int nbh = B * N_HEADS;
    int nqt = T / 128;
    int bh, qt;
    if (nbh == 16 && nqt == 32) {
        int xcd = n & 7, s = n >> 3;
        bh = xcd * 2 + (s >> 5);
        qt = s & 31;
    } else {
        bh = n / nqt;
        qt = n % nqt;
    }
    int hh = bh & (N_HEADS - 1), b = bh >> 3;
    int qr0 = qt * 128;

    const char* kbase = (const char*)(k + (size_t)bh * T * DK);
    const char* vbase = (const char*)(v + (size_t)bh * DK * T);

    // staging addresses: LDS linear dest, inverse-swizzled global source
    int lin0 = w * 1024 + lane * 16;
    int lin1 = 4096 + lin0;
    int row0 = lin0 >> 7, row1 = lin1 >> 7;
    int sw0 = (row0 & 7) << 4, sw1 = (row1 & 7) << 4;
    const char* gK0 = kbase + (lin0 ^ sw0);
    const char* gK1 = kbase + (lin1 ^ sw1);
    const char* gV0 = vbase + (size_t)row0 * (2 * T) + ((lin0 & 127) ^ sw0);
    const char* gV1 = vbase + (size_t)row1 * (2 * T) + ((lin1 & 127) ^ sw1);

    // Q B-fragments: lane holds Q[q = qr0 + w*32 + ln][ks*16 + hi*8 .. +7]
    short8 qfr[4];
    {
        const unsigned short* qrow = q + ((size_t)bh * T + qr0 + w * 32 + ln) * DK + hi * 8;
        #pragma unroll
        for (int ks = 0; ks < 4; ks++)
            qfr[ks] = *(const short8*)(qrow + ks * 16);
    }

    // ones B-fragment (bf16 1.0) for l-MFMA
    short8 ones;
    #pragma unroll
    for (int i = 0; i < 8; i++) ones[i] = (short)0x3F80;

    // mask: lane's q-row, strided dwords (kcol = rb*32 + g*8 + 4*hi + 0..3)
    const unsigned char* mbase = mu + (size_t)(qr0 + w * 32 + ln) * T + 4 * hi;

    f32x16 oacc[2], oacc_l;
    #pragma unroll
    for (int db = 0; db < 2; db++)
        #pragma unroll
        for (int i = 0; i < 16; i++) oacc[db][i] = 0.f;
    #pragma unroll
    for (int i = 0; i < 16; i++) oacc_l[i] = 0.f;

    short8 pa[4];   // carried P fragments (tile t-1)
    #pragma unroll
    for (int i = 0; i < 4; i++) pa[i] = ones;   // dummy init; guarded by kt>0

    // prologue: mask tile 0 + stage K0 -> Ks[0], V0 -> Vt[0]
    unsigned mcur[8];
    #pragma unroll
    for (int rb = 0; rb < 2; rb++)
        #pragma unroll
        for (int g = 0; g < 4; g++)
            mcur[rb * 4 + g] = *(const unsigned*)(mbase + rb * 32 + g * 8);
    __builtin_amdgcn_global_load_lds((as1_uint*)gK0, (as3_uint*)((char*)&Ks[0][0] + lin0), 16, 0, 0);
    __builtin_amdgcn_global_load_lds((as1_uint*)gK1, (as3_uint*)((char*)&Ks[0][0] + lin1), 16, 0, 0);
    __builtin_amdgcn_global_load_lds((as1_uint*)gV0, (as3_uint*)((char*)&Vt[0][0] + lin0), 16, 0, 0);
    __builtin_amdgcn_global_load_lds((as1_uint*)gV1, (as3_uint*)((char*)&Vt[0][0] + lin1), 16, 0, 0);

    int ntiles = T / 64;
    int vc = 0;                    // Vt index of tile kt
    for (int kt = 0; kt < ntiles; kt++) {
        __syncthreads();           // K(kt),V(kt) staged; all prev-tile reads done
        int kcur = kt & 1;
        int vp = (vc + 2) % 3;     // Vt index of tile kt-1
        int vn = (vc + 1) % 3;     // Vt index of tile kt+1
        bool havenext = (kt + 1) < ntiles;

        unsigned mnxt[8];
        if (havenext) {
            const unsigned char* mp = mbase + (size_t)(kt + 1) * 64;
            #pragma unroll
            for (int rb = 0; rb < 2; rb++)
                #pragma unroll
                for (int g = 0; g < 4; g++)
                    mnxt[rb * 4 + g] = *(const unsigned*)(mp + rb * 32 + g * 8);
            size_t ko = (size_t)(kt + 1) * 8192;
            size_t vo = (size_t)(kt + 1) * 128;
            __builtin_amdgcn_global_load_lds((as1_uint*)(gK0 + ko),
                (as3_uint*)((char*)&Ks[kcur ^ 1][0] + lin0), 16, 0, 0);
            __builtin_amdgcn_global_load_lds((as1_uint*)(gK1 + ko),
                (as3_uint*)((char*)&Ks[kcur ^ 1][0] + lin1), 16, 0, 0);
            __builtin_amdgcn_global_load_lds((as1_uint*)(gV0 + vo),
                (as3_uint*)((char*)&Vt[vn][0] + lin0), 16, 0, 0);
            __builtin_amdgcn_global_load_lds((as1_uint*)(gV1 + vo),
                (as3_uint*)((char*)&Vt[vn][0] + lin1), 16, 0, 0);
        }

        // QK^T (swapped): sacc[rb][reg] = S[kcol = rb*32 + (reg&3)+8*(reg>>2)+4*hi][q = ln]
        f32x16 sacc[2];
        #pragma unroll
        for (int rb = 0; rb < 2; rb++)
            #pragma unroll
            for (int i = 0; i < 16; i++) sacc[rb][i] = 0.f;
        __builtin_amdgcn_s_setprio(1);
        #pragma unroll
        for (int ks = 0; ks < 4; ks++) {
            #pragma unroll
            for (int rb = 0; rb < 2; rb++) {
                int row = rb * 32 + ln;
                short8 kf = *(const short8*)((const char*)&Ks[kcur][0] +
                            ((row * 128 + ks * 32 + hi * 16) ^ ((row & 7) << 4)));
                sacc[rb] = __builtin_amdgcn_mfma_f32_32x32x16_bf16(kf, qfr[ks], sacc[rb], 0, 0, 0);
            }
        }

        // PV(kt-1): independent of QK(kt) -> fills matrix pipe during QK latency
        if (kt > 0) {
            #pragma unroll
            for (int ks = 0; ks < 4; ks++) {
                #pragma unroll
                for (int db = 0; db < 2; db++) {
                    int row = db * 32 + ln;
                    short8 vb = *(const short8*)((const char*)&Vt[vp][0] +
                                ((row * 128 + ks * 32 + hi * 16) ^ ((row & 7) << 4)));
                    oacc[db] = __builtin_amdgcn_mfma_f32_32x32x16_bf16(pa[ks], vb, oacc[db], 0, 0, 0);
                }
                oacc_l = __builtin_amdgcn_mfma_f32_32x32x16_bf16(pa[ks], ones, oacc_l, 0, 0, 0);
            }
        }
        __builtin_amdgcn_s_setprio(0);

        // softmax(kt): p = exp2(s*m); build next pa in-register (cvt_pk + permlane32_swap)
        #pragma unroll
        for (int rb = 0; rb < 2; rb++) {
            float p[16];
            #pragma unroll
            for (int g = 0; g < 4; g++) {
                unsigned mw = mcur[rb * 4 + g];
                float p0 = __builtin_amdgcn_exp2f(sacc[rb][g * 4 + 0] * (float)(mw & 0xffu));
                float p1 = __builtin_amdgcn_exp2f(sacc[rb][g * 4 + 1] * (float)((mw >> 8) & 0xffu));
                float p2 = __builtin_amdgcn_exp2f(sacc[rb][g * 4 + 2] * (float)((mw >> 16) & 0xffu));
                float p3 = __builtin_amdgcn_exp2f(sacc[rb][g * 4 + 3] * (float)(mw >> 24));
                p[g * 4 + 0] = p0; p[g * 4 + 1] = p1; p[g * 4 + 2] = p2; p[g * 4 + 3] = p3;
            }
            #pragma unroll
            for (int kl = 0; kl < 2; kl++) {
                int b0 = kl * 8;
                unsigned d0, d1, d2, d3;
                asm("v_cvt_pk_bf16_f32 %0, %1, %2" : "=v"(d0) : "v"(p[b0 + 0]), "v"(p[b0 + 1]));
                asm("v_cvt_pk_bf16_f32 %0, %1, %2" : "=v"(d1) : "v"(p[b0 + 2]), "v"(p[b0 + 3]));
                asm("v_cvt_pk_bf16_f32 %0, %1, %2" : "=v"(d2) : "v"(p[b0 + 4]), "v"(p[b0 + 5]));
                asm("v_cvt_pk_bf16_f32 %0, %1, %2" : "=v"(d3) : "v"(p[b0 + 6]), "v"(p[b0 + 7]));
                asm("v_permlane32_swap_b32 %0, %1" : "+v"(d0), "+v"(d2));
                asm("v_permlane32_swap_b32 %0, %1" : "+v"(d1), "+v"(d3));
                uint4 fr = { d0, d1, d2, d3 };
                pa[rb * 2 + kl] = __builtin_bit_cast(short8, fr);
            }
        }

        if (havenext) {
            #pragma unroll
            for (int c = 0; c < 8; c++) mcur[c] = mnxt[c];
        }
        vc = vn;
    }

    // epilogue: PV(ntiles-1) — Vt[(ntiles-1)%3] = index (vc+2)%3 after final rotate
    {
        int vp = (vc + 2) % 3;
        __builtin_amdgcn_s_setprio(1);
        #pragma unroll
        for (int ks = 0; ks < 4; ks++) {
            #pragma unroll
            for (int db = 0; db < 2; db++) {
                int row = db * 32 + ln;
                short8 vb = *(const short8*)((const char*)&Vt[vp][0] +
                            ((row * 128 + ks * 32 + hi * 16) ^ ((row & 7) << 4)));
                oacc[db] = __builtin_amdgcn_mfma_f32_32x32x16_bf16(pa[ks], vb, oacc[db], 0, 0, 0);
            }
            oacc_l = __builtin_amdgcn_mfma_f32_32x32x16_bf16(pa[ks], ones, oacc_l, 0, 0, 0);
        }
        __builtin_amdgcn_s_setprio(0);
    }

    // store: oacc[db][reg] is O[q = (reg&3)+8*(reg>>2)+4*hi][d = db*32 + ln];
    // oacc_l[reg] holds l[q] in the SAME layout -> shfl-free normalize.
    #pragma unroll
    for (int reg = 0; reg < 16; reg++) {
        int qoff = (reg & 3) + 8 * (reg >> 2) + 4 * hi;
        float linv = 1.0f / oacc_l[reg];
        size_t rowo = ((size_t)b * T + qr0 + w * 32 + qoff) * D_MODEL + hh * DK + ln;
        out[rowo]      = f2bf(oacc[0][reg] * linv);
        out[rowo + 32] = f2bf(oacc[1][reg] * linv);
    }
}

extern "C" void kernel_launch(void* const* d_in, const int* in_sizes, int n_in,
                              void* d_out, int out_size, void* d_ws, size_t ws_size,
                              hipStream_t stream) {
    const float* x    = (const float*)d_in[0];
    const float* mask = (const float*)d_in[1];
    const float* Wq   = (const float*)d_in[2];
    const float* bq   = (const float*)d_in[3];
    const float* Wk   = (const float*)d_in[4];
    const float* bk   = (const float*)d_in[5];
    const float* Wv   = (const float*)d_in[6];
    const float* bv   = (const float*)d_in[7];
    const float* Wo   = (const float*)d_in[8];
    const float* bo   = (const float*)d_in[9];

    int T = (int)(sqrt((double)in_sizes[1]) + 0.5);   // 4096
    int C = D_MODEL;
    int B = in_sizes[0] / (T * C);                    // 2
    int M = B * T;

    size_t MK = (size_t)M * C;
    unsigned short* xb  = (unsigned short*)d_ws;
    unsigned short* Wtq = xb + MK;                    // [2048][512]: q,k,v,o contiguous
    unsigned short* Wto = Wtq + 3 * (size_t)C * C;
    unsigned short* qb  = Wtq + 4 * (size_t)C * C;
    unsigned short* kb  = qb + MK;
    unsigned short* vb  = kb + MK;
    unsigned short* attb = vb + MK;
    unsigned char*  mu  = (unsigned char*)(attb + MK);

    int n8 = (int)(MK / 8);
    cvt_x_kernel<<<(n8 + 255) / 256, 256, 0, stream>>>(x, xb, n8);
    int n4 = T * T / 4;
    cvt_mask_kernel<<<(n4 + 255) / 256, 256, 0, stream>>>(mask, mu, n4);
    dim3 wtg(C / 64, C / 64, 4);
    cvt_wt4_kernel<<<wtg, 256, 0, stream>>>(Wq, Wk, Wv, Wo, Wtq);

    dim3 gq(3 * C / 128, M / 128, 1);
    gemm_qkv_kernel<<<gq, 512, 0, stream>>>(xb, Wtq, bq, bk, bv, qb, kb, vb, M, T);

    int nblocks = (B * N_HEADS) * (T / 128);
    attn_mfma_kernel<<<nblocks, 256, 0, stream>>>(qb, kb, vb, mu, attb, B, T);

    dim3 gg(C / 128, M / 128, 1);
    gemm_out_kernel<<<gg, 512, 0, stream>>>(attb, Wto, bo, (float*)d_out, M);
}

// Round 16
// 207.817 us; speedup vs baseline: 1.1061x; 1.0044x over previous
//
#include <hip/hip_runtime.h>
#include <math.h>

#define D_MODEL 512
#define N_HEADS 8
#define DK 64
#define QSCALE (0.0625f * 1.44269504089f)

typedef __attribute__((ext_vector_type(8))) short short8;
typedef __attribute__((ext_vector_type(4))) float f32x4;
typedef __attribute__((ext_vector_type(16))) float f32x16;

typedef __attribute__((address_space(1))) const unsigned as1_uint;
typedef __attribute__((address_space(3))) unsigned as3_uint;

__device__ __forceinline__ unsigned short f2bf(float f) {
    unsigned u = __builtin_bit_cast(unsigned, f);
    u = (u + 0x7fff + ((u >> 16) & 1)) >> 16;   // RNE
    return (unsigned short)u;
}

// ---------------- x fp32 -> bf16 ----------------
__global__ __launch_bounds__(256) void cvt_x_kernel(const float* __restrict__ x,
                                                    unsigned short* __restrict__ xb, int n8)
{
    int i = blockIdx.x * 256 + threadIdx.x;
    if (i >= n8) return;
    float4 a = ((const float4*)x)[i * 2];
    float4 b = ((const float4*)x)[i * 2 + 1];
    short8 o;
    o[0] = f2bf(a.x); o[1] = f2bf(a.y); o[2] = f2bf(a.z); o[3] = f2bf(a.w);
    o[4] = f2bf(b.x); o[5] = f2bf(b.y); o[6] = f2bf(b.z); o[7] = f2bf(b.w);
    ((short8*)xb)[i] = o;
}

// ---------------- mask fp32 {0,0.5,1} -> u8 {0,1,2}, 16 elems/thread ----------------
__global__ __launch_bounds__(256) void cvt_mask_kernel(const float* __restrict__ m,
                                                       unsigned char* __restrict__ mu, int n16)
{
    int i = blockIdx.x * 256 + threadIdx.x;
    if (i >= n16) return;
    uchar4 o[4];
    #pragma unroll
    for (int j = 0; j < 4; j++) {
        float4 v = ((const float4*)m)[i * 4 + j];
        o[j].x = (unsigned char)(v.x * 2.0f + 0.5f);
        o[j].y = (unsigned char)(v.y * 2.0f + 0.5f);
        o[j].z = (unsigned char)(v.z * 2.0f + 0.5f);
        o[j].w = (unsigned char)(v.w * 2.0f + 0.5f);
    }
    ((uint4*)mu)[i] = *(uint4*)&o[0];
}

// ---------------- W [K][N] fp32 -> Wt [N][K] bf16 (all 4 in one launch) ----------------
__global__ __launch_bounds__(256) void cvt_wt4_kernel(
    const float* __restrict__ Wq, const float* __restrict__ Wk,
    const float* __restrict__ Wv, const float* __restrict__ Wo,
    unsigned short* __restrict__ Wt)
{
    __shared__ float tile[64][65];
    int z = blockIdx.z;
    const float* W = (z == 0) ? Wq : (z == 1) ? Wk : (z == 2) ? Wv : Wo;
    unsigned short* dst = Wt + (size_t)z * D_MODEL * D_MODEL;
    int t = threadIdx.x;
    int c0 = blockIdx.x * 64;   // n
    int r0 = blockIdx.y * 64;   // k
    #pragma unroll
    for (int i = 0; i < 16; i++) {
        int e = i * 256 + t, r = e >> 6, c = e & 63;
        tile[c][r] = W[(size_t)(r0 + r) * D_MODEL + c0 + c];
    }
    __syncthreads();
    #pragma unroll
    for (int i = 0; i < 16; i++) {
        int e = i * 256 + t, n = e >> 6, kk = e & 63;
        dst[(size_t)(c0 + n) * D_MODEL + r0 + kk] = f2bf(tile[n][kk]);
    }
}

// ---------------- fused QKV GEMM: [q|k|v] = x @ [Wq|Wk|Wv] + b ----------------
__global__ __launch_bounds__(512) void gemm_qkv_kernel(
    const unsigned short* __restrict__ A, const unsigned short* __restrict__ Wt,
    const float* __restrict__ bq, const float* __restrict__ bk, const float* __restrict__ bv,
    unsigned short* __restrict__ qb, unsigned short* __restrict__ kb,
    unsigned short* __restrict__ vb, int M, int T)
{
    constexpr int K = D_MODEL;
    __shared__ unsigned short As[2][128 * 32];
    __shared__ unsigned short Bs[2][128 * 32];
    int t = threadIdx.x;
    int lane = t & 63, w = t >> 6;
    int ql = lane & 15, kg = lane >> 4;
    int m0 = blockIdx.y * 128, n0 = blockIdx.x * 128;
    int wm = w >> 2, wn = w & 3;
    bool vmode = (n0 >= 1024);

    const unsigned short* srcA = A + (size_t)(m0 + (t >> 2)) * K + (t & 3) * 8;
    const unsigned short* srcB = Wt + (size_t)(n0 + (t >> 2)) * K + (t & 3) * 8;

    f32x4 acc[4][2];
    #pragma unroll
    for (int i = 0; i < 4; i++)
        #pragma unroll
        for (int j = 0; j < 2; j++) { f32x4 z = {0.f, 0.f, 0.f, 0.f}; acc[i][j] = z; }

    constexpr int NIT = K / 32;
    int cur = 0;
    __builtin_amdgcn_global_load_lds((as1_uint*)(srcA),
        (as3_uint*)((char*)&As[0][0] + w * 1024), 16, 0, 0);
    __builtin_amdgcn_global_load_lds((as1_uint*)(srcB),
        (as3_uint*)((char*)&Bs[0][0] + w * 1024), 16, 0, 0);
    __syncthreads();

    for (int it = 0; it < NIT; ++it) {
        if (it + 1 < NIT) {
            int k0 = (it + 1) * 32;
            __builtin_amdgcn_global_load_lds((as1_uint*)(srcA + k0),
                (as3_uint*)((char*)&As[cur ^ 1][0] + w * 1024), 16, 0, 0);
            __builtin_amdgcn_global_load_lds((as1_uint*)(srcB + k0),
                (as3_uint*)((char*)&Bs[cur ^ 1][0] + w * 1024), 16, 0, 0);
        }
        short8 af[4], bfr[2];
        #pragma unroll
        for (int fm = 0; fm < 4; fm++)
            af[fm] = *(const short8*)((const char*)&As[cur][0] + (wm * 64 + fm * 16 + ql) * 64 + kg * 16);
        #pragma unroll
        for (int fn = 0; fn < 2; fn++)
            bfr[fn] = *(const short8*)((const char*)&Bs[cur][0] + (wn * 32 + fn * 16 + ql) * 64 + kg * 16);
        if (vmode) {
            #pragma unroll
            for (int fm = 0; fm < 4; fm++)
                #pragma unroll
                for (int fn = 0; fn < 2; fn++)
                    acc[fm][fn] = __builtin_amdgcn_mfma_f32_16x16x32_bf16(bfr[fn], af[fm], acc[fm][fn], 0, 0, 0);
        } else {
            #pragma unroll
            for (int fm = 0; fm < 4; fm++)
                #pragma unroll
                for (int fn = 0; fn < 2; fn++)
                    acc[fm][fn] = __builtin_amdgcn_mfma_f32_16x16x32_bf16(af[fm], bfr[fn], acc[fm][fn], 0, 0, 0);
        }
        __syncthreads();
        cur ^= 1;
    }

    #pragma unroll
    for (int fm = 0; fm < 4; fm++) {
        #pragma unroll
        for (int fn = 0; fn < 2; fn++) {
            if (vmode) {
                int m = m0 + wm * 64 + fm * 16 + ql;
                int b = m / T, tt = m % T;
                #pragma unroll
                for (int r = 0; r < 4; r++) {
                    int n = (n0 - 1024) + wn * 32 + fn * 16 + kg * 4 + r;
                    float val = acc[fm][fn][r] + bv[n];
                    int h = n >> 6, d = n & 63;
                    vb[((size_t)(b * N_HEADS + h) * DK + d) * T + tt] = f2bf(val);
                }
            } else {
                int n = n0 + wn * 32 + fn * 16 + ql;
                int nn = n & 511;
                bool isq = (n0 < 512);
                float bn = isq ? bq[nn] : bk[nn];
                unsigned short* dst = isq ? qb : kb;
                int h = nn >> 6, d = nn & 63;
                #pragma unroll
                for (int r = 0; r < 4; r++) {
                    int m = m0 + wm * 64 + fm * 16 + kg * 4 + r;
                    int b = m / T, tt = m % T;
                    float val = acc[fm][fn][r] + bn;
                    if (isq) val *= QSCALE;
                    dst[((size_t)(b * N_HEADS + h) * T + tt) * DK + d] = f2bf(val);
                }
            }
        }
    }
}

// ---------------- out-proj GEMM: fp32 out = attb @ Wo + bo ----------------
__global__ __launch_bounds__(512) void gemm_out_kernel(
    const unsigned short* __restrict__ A, const unsigned short* __restrict__ Bt,
    const float* __restrict__ bias, float* __restrict__ outp, int M)
{
    constexpr int K = D_MODEL;
    __shared__ unsigned short As[2][128 * 32];
    __shared__ unsigned short Bs[2][128 * 32];
    int t = threadIdx.x;
    int lane = t & 63, w = t >> 6;
    int ql = lane & 15, kg = lane >> 4;
    int m0 = blockIdx.y * 128, n0 = blockIdx.x * 128;
    int wm = w >> 2, wn = w & 3;

    const unsigned short* srcA = A + (size_t)(m0 + (t >> 2)) * K + (t & 3) * 8;
    const unsigned short* srcB = Bt + (size_t)(n0 + (t >> 2)) * K + (t & 3) * 8;

    f32x4 acc[4][2];
    #pragma unroll
    for (int i = 0; i < 4; i++)
        #pragma unroll
        for (int j = 0; j < 2; j++) { f32x4 z = {0.f, 0.f, 0.f, 0.f}; acc[i][j] = z; }

    constexpr int NIT = K / 32;
    int cur = 0;
    __builtin_amdgcn_global_load_lds((as1_uint*)(srcA),
        (as3_uint*)((char*)&As[0][0] + w * 1024), 16, 0, 0);
    __builtin_amdgcn_global_load_lds((as1_uint*)(srcB),
        (as3_uint*)((char*)&Bs[0][0] + w * 1024), 16, 0, 0);
    __syncthreads();

    for (int it = 0; it < NIT; ++it) {
        if (it + 1 < NIT) {
            int k0 = (it + 1) * 32;
            __builtin_amdgcn_global_load_lds((as1_uint*)(srcA + k0),
                (as3_uint*)((char*)&As[cur ^ 1][0] + w * 1024), 16, 0, 0);
            __builtin_amdgcn_global_load_lds((as1_uint*)(srcB + k0),
                (as3_uint*)((char*)&Bs[cur ^ 1][0] + w * 1024), 16, 0, 0);
        }
        short8 af[4], bfr[2];
        #pragma unroll
        for (int fm = 0; fm < 4; fm++)
            af[fm] = *(const short8*)((const char*)&As[cur][0] + (wm * 64 + fm * 16 + ql) * 64 + kg * 16);
        #pragma unroll
        for (int fn = 0; fn < 2; fn++)
            bfr[fn] = *(const short8*)((const char*)&Bs[cur][0] + (wn * 32 + fn * 16 + ql) * 64 + kg * 16);
        #pragma unroll
        for (int fm = 0; fm < 4; fm++)
            #pragma unroll
            for (int fn = 0; fn < 2; fn++)
                acc[fm][fn] = __builtin_amdgcn_mfma_f32_16x16x32_bf16(af[fm], bfr[fn], acc[fm][fn], 0, 0, 0);
        __syncthreads();
        cur ^= 1;
    }

    #pragma unroll
    for (int fm = 0; fm < 4; fm++) {
        #pragma unroll
        for (int fn = 0; fn < 2; fn++) {
            int n = n0 + wn * 32 + fn * 16 + ql;
            float bn = bias[n];
            #pragma unroll
            for (int r = 0; r < 4; r++) {
                int m = m0 + wm * 64 + fm * 16 + kg * 4 + r;
                outp[(size_t)m * D_MODEL + n] = acc[fm][fn][r] + bn;
            }
        }
    }
}

// ---------------- MFMA flash attention v14 (certified best): pipelined PV(t-1) + MFMA l ----------------
__global__ __launch_bounds__(256) void attn_mfma_kernel(
    const unsigned short* __restrict__ q, const unsigned short* __restrict__ k,
    const unsigned short* __restrict__ v, const unsigned char* __restrict__ mu,
    unsigned short* __restrict__ out, int B, int T)
{
    __shared__ unsigned short Ks[2][64 * 64];
    __shared__ unsigned short Vt[3][64 * 64];

    int t = threadIdx.x;
    int lane = t & 63, w = t >> 6;
    int ln = lane & 31, hi = lane >> 5;

    // XCD-aware decode of linear block id (dispatch: block i -> XCD i%8)
    int n = blockIdx.x;
    int nbh = B * N_HEADS;
    int nqt = T / 128;
    int bh, qt;
    if (nbh == 16 && nqt == 32) {
        int xcd = n & 7, s = n >> 3;
        bh = xcd * 2 + (s >> 5);
        qt = s & 31;
    } else {
        bh = n / nqt;
        qt = n % nqt;
    }
    int hh = bh & (N_HEADS - 1), b = bh >> 3;
    int qr0 = qt * 128;

    const char* kbase = (const char*)(k + (size_t)bh * T * DK);
    const char* vbase = (const char*)(v + (size_t)bh * DK * T);

    // staging addresses: LDS linear dest, inverse-swizzled global source
    int lin0 = w * 1024 + lane * 16;
    int lin1 = 4096 + lin0;
    int row0 = lin0 >> 7, row1 = lin1 >> 7;
    int sw0 = (row0 & 7) << 4, sw1 = (row1 & 7) << 4;
    const char* gK0 = kbase + (lin0 ^ sw0);
    const char* gK1 = kbase + (lin1 ^ sw1);
    const char* gV0 = vbase + (size_t)row0 * (2 * T) + ((lin0 & 127) ^ sw0);
    const char* gV1 = vbase + (size_t)row1 * (2 * T) + ((lin1 & 127) ^ sw1);

    // Q B-fragments: lane holds Q[q = qr0 + w*32 + ln][ks*16 + hi*8 .. +7]
    short8 qfr[4];
    {
        const unsigned short* qrow = q + ((size_t)bh * T + qr0 + w * 32 + ln) * DK + hi * 8;
        #pragma unroll
        for (int ks = 0; ks < 4; ks++)
            qfr[ks] = *(const short8*)(qrow + ks * 16);
    }

    // ones B-fragment (bf16 1.0) for l-MFMA
    short8 ones;
    #pragma unroll
    for (int i = 0; i < 8; i++) ones[i] = (short)0x3F80;

    // mask: lane's q-row, strided dwords (kcol = rb*32 + g*8 + 4*hi + 0..3)
    const unsigned char* mbase = mu + (size_t)(qr0 + w * 32 + ln) * T + 4 * hi;

    f32x16 oacc[2], oacc_l;
    #pragma unroll
    for (int db = 0; db < 2; db++)
        #pragma unroll
        for (int i = 0; i < 16; i++) oacc[db][i] = 0.f;
    #pragma unroll
    for (int i = 0; i < 16; i++) oacc_l[i] = 0.f;

    short8 pa[4];   // carried P fragments (tile t-1)
    #pragma unroll
    for (int i = 0; i < 4; i++) pa[i] = ones;   // dummy init; guarded by kt>0

    // prologue: mask tile 0 + stage K0 -> Ks[0], V0 -> Vt[0]
    unsigned mcur[8];
    #pragma unroll
    for (int rb = 0; rb < 2; rb++)
        #pragma unroll
        for (int g = 0; g < 4; g++)
            mcur[rb * 4 + g] = *(const unsigned*)(mbase + rb * 32 + g * 8);
    __builtin_amdgcn_global_load_lds((as1_uint*)gK0, (as3_uint*)((char*)&Ks[0][0] + lin0), 16, 0, 0);
    __builtin_amdgcn_global_load_lds((as1_uint*)gK1, (as3_uint*)((char*)&Ks[0][0] + lin1), 16, 0, 0);
    __builtin_amdgcn_global_load_lds((as1_uint*)gV0, (as3_uint*)((char*)&Vt[0][0] + lin0), 16, 0, 0);
    __builtin_amdgcn_global_load_lds((as1_uint*)gV1, (as3_uint*)((char*)&Vt[0][0] + lin1), 16, 0, 0);

    int ntiles = T / 64;
    int vc = 0;                    // Vt index of tile kt
    for (int kt = 0; kt < ntiles; kt++) {
        __syncthreads();           // K(kt),V(kt) staged; all prev-tile reads done
        int kcur = kt & 1;
        int vp = (vc + 2) % 3;     // Vt index of tile kt-1
        int vn = (vc + 1) % 3;     // Vt index of tile kt+1
        bool havenext = (kt + 1) < ntiles;

        unsigned mnxt[8];
        if (havenext) {
            const unsigned char* mp = mbase + (size_t)(kt + 1) * 64;
            #pragma unroll
            for (int rb = 0; rb < 2; rb++)
                #pragma unroll
                for (int g = 0; g < 4; g++)
                    mnxt[rb * 4 + g] = *(const unsigned*)(mp + rb * 32 + g * 8);
            size_t ko = (size_t)(kt + 1) * 8192;
            size_t vo = (size_t)(kt + 1) * 128;
            __builtin_amdgcn_global_load_lds((as1_uint*)(gK0 + ko),
                (as3_uint*)((char*)&Ks[kcur ^ 1][0] + lin0), 16, 0, 0);
            __builtin_amdgcn_global_load_lds((as1_uint*)(gK1 + ko),
                (as3_uint*)((char*)&Ks[kcur ^ 1][0] + lin1), 16, 0, 0);
            __builtin_amdgcn_global_load_lds((as1_uint*)(gV0 + vo),
                (as3_uint*)((char*)&Vt[vn][0] + lin0), 16, 0, 0);
            __builtin_amdgcn_global_load_lds((as1_uint*)(gV1 + vo),
                (as3_uint*)((char*)&Vt[vn][0] + lin1), 16, 0, 0);
        }

        // QK^T (swapped): sacc[rb][reg] = S[kcol = rb*32 + (reg&3)+8*(reg>>2)+4*hi][q = ln]
        f32x16 sacc[2];
        #pragma unroll
        for (int rb = 0; rb < 2; rb++)
            #pragma unroll
            for (int i = 0; i < 16; i++) sacc[rb][i] = 0.f;
        __builtin_amdgcn_s_setprio(1);
        #pragma unroll
        for (int ks = 0; ks < 4; ks++) {
            #pragma unroll
            for (int rb = 0; rb < 2; rb++) {
                int row = rb * 32 + ln;
                short8 kf = *(const short8*)((const char*)&Ks[kcur][0] +
                            ((row * 128 + ks * 32 + hi * 16) ^ ((row & 7) << 4)));
                sacc[rb] = __builtin_amdgcn_mfma_f32_32x32x16_bf16(kf, qfr[ks], sacc[rb], 0, 0, 0);
            }
        }

        // PV(kt-1): independent of QK(kt) -> fills matrix pipe during QK latency
        if (kt > 0) {
            #pragma unroll
            for (int ks = 0; ks < 4; ks++) {
                #pragma unroll
                for (int db = 0; db < 2; db++) {
                    int row = db * 32 + ln;
                    short8 vb = *(const short8*)((const char*)&Vt[vp][0] +
                                ((row * 128 + ks * 32 + hi * 16) ^ ((row & 7) << 4)));
                    oacc[db] = __builtin_amdgcn_mfma_f32_32x32x16_bf16(pa[ks], vb, oacc[db], 0, 0, 0);
                }
                oacc_l = __builtin_amdgcn_mfma_f32_32x32x16_bf16(pa[ks], ones, oacc_l, 0, 0, 0);
            }
        }
        __builtin_amdgcn_s_setprio(0);

        // softmax(kt): p = exp2(s*m); build next pa in-register (cvt_pk + permlane32_swap)
        #pragma unroll
        for (int rb = 0; rb < 2; rb++) {
            float p[16];
            #pragma unroll
            for (int g = 0; g < 4; g++) {
                unsigned mw = mcur[rb * 4 + g];
                float p0 = __builtin_amdgcn_exp2f(sacc[rb][g * 4 + 0] * (float)(mw & 0xffu));
                float p1 = __builtin_amdgcn_exp2f(sacc[rb][g * 4 + 1] * (float)((mw >> 8) & 0xffu));
                float p2 = __builtin_amdgcn_exp2f(sacc[rb][g * 4 + 2] * (float)((mw >> 16) & 0xffu));
                float p3 = __builtin_amdgcn_exp2f(sacc[rb][g * 4 + 3] * (float)(mw >> 24));
                p[g * 4 + 0] = p0; p[g * 4 + 1] = p1; p[g * 4 + 2] = p2; p[g * 4 + 3] = p3;
            }
            #pragma unroll
            for (int kl = 0; kl < 2; kl++) {
                int b0 = kl * 8;
                unsigned d0, d1, d2, d3;
                asm("v_cvt_pk_bf16_f32 %0, %1, %2" : "=v"(d0) : "v"(p[b0 + 0]), "v"(p[b0 + 1]));
                asm("v_cvt_pk_bf16_f32 %0, %1, %2" : "=v"(d1) : "v"(p[b0 + 2]), "v"(p[b0 + 3]));
                asm("v_cvt_pk_bf16_f32 %0, %1, %2" : "=v"(d2) : "v"(p[b0 + 4]), "v"(p[b0 + 5]));
                asm("v_cvt_pk_bf16_f32 %0, %1, %2" : "=v"(d3) : "v"(p[b0 + 6]), "v"(p[b0 + 7]));
                asm("v_permlane32_swap_b32 %0, %1" : "+v"(d0), "+v"(d2));
                asm("v_permlane32_swap_b32 %0, %1" : "+v"(d1), "+v"(d3));
                uint4 fr = { d0, d1, d2, d3 };
                pa[rb * 2 + kl] = __builtin_bit_cast(short8, fr);
            }
        }

        if (havenext) {
            #pragma unroll
            for (int c = 0; c < 8; c++) mcur[c] = mnxt[c];
        }
        vc = vn;
    }

    // epilogue: PV(ntiles-1)
    {
        int vp = (vc + 2) % 3;
        __builtin_amdgcn_s_setprio(1);
        #pragma unroll
        for (int ks = 0; ks < 4; ks++) {
            #pragma unroll
            for (int db = 0; db < 2; db++) {
                int row = db * 32 + ln;
                short8 vb = *(const short8*)((const char*)&Vt[vp][0] +
                            ((row * 128 + ks * 32 + hi * 16) ^ ((row & 7) << 4)));
                oacc[db] = __builtin_amdgcn_mfma_f32_32x32x16_bf16(pa[ks], vb, oacc[db], 0, 0, 0);
            }
            oacc_l = __builtin_amdgcn_mfma_f32_32x32x16_bf16(pa[ks], ones, oacc_l, 0, 0, 0);
        }
        __builtin_amdgcn_s_setprio(0);
    }

    // store: oacc[db][reg] is O[q = (reg&3)+8*(reg>>2)+4*hi][d = db*32 + ln];
    // oacc_l[reg] holds l[q] in the SAME layout -> shfl-free normalize.
    #pragma unroll
    for (int reg = 0; reg < 16; reg++) {
        int qoff = (reg & 3) + 8 * (reg >> 2) + 4 * hi;
        float linv = 1.0f / oacc_l[reg];
        size_t rowo = ((size_t)b * T + qr0 + w * 32 + qoff) * D_MODEL + hh * DK + ln;
        out[rowo]      = f2bf(oacc[0][reg] * linv);
        out[rowo + 32] = f2bf(oacc[1][reg] * linv);
    }
}

extern "C" void kernel_launch(void* const* d_in, const int* in_sizes, int n_in,
                              void* d_out, int out_size, void* d_ws, size_t ws_size,
                              hipStream_t stream) {
    const float* x    = (const float*)d_in[0];
    const float* mask = (const float*)d_in[1];
    const float* Wq   = (const float*)d_in[2];
    const float* bq   = (const float*)d_in[3];
    const float* Wk   = (const float*)d_in[4];
    const float* bk   = (const float*)d_in[5];
    const float* Wv   = (const float*)d_in[6];
    const float* bv   = (const float*)d_in[7];
    const float* Wo   = (const float*)d_in[8];
    const float* bo   = (const float*)d_in[9];

    int T = (int)(sqrt((double)in_sizes[1]) + 0.5);   // 4096
    int C = D_MODEL;
    int B = in_sizes[0] / (T * C);                    // 2
    int M = B * T;

    size_t MK = (size_t)M * C;
    unsigned short* xb  = (unsigned short*)d_ws;
    unsigned short* Wtq = xb + MK;                    // [2048][512]: q,k,v,o contiguous
    unsigned short* Wto = Wtq + 3 * (size_t)C * C;
    unsigned short* qb  = Wtq + 4 * (size_t)C * C;
    unsigned short* kb  = qb + MK;
    unsigned short* vb  = kb + MK;
    unsigned short* attb = vb + MK;
    unsigned char*  mu  = (unsigned char*)(attb + MK);

    int n8 = (int)(MK / 8);
    cvt_x_kernel<<<(n8 + 255) / 256, 256, 0, stream>>>(x, xb, n8);
    int n16 = T * T / 16;
    cvt_mask_kernel<<<(n16 + 255) / 256, 256, 0, stream>>>(mask, mu, n16);
    dim3 wtg(C / 64, C / 64, 4);
    cvt_wt4_kernel<<<wtg, 256, 0, stream>>>(Wq, Wk, Wv, Wo, Wtq);

    dim3 gq(3 * C / 128, M / 128, 1);
    gemm_qkv_kernel<<<gq, 512, 0, stream>>>(xb, Wtq, bq, bk, bv, qb, kb, vb, M, T);

    int nblocks = (B * N_HEADS) * (T / 128);
    attn_mfma_kernel<<<nblocks, 256, 0, stream>>>(qb, kb, vb, mu, attb, B, T);

    dim3 gg(C / 128, M / 128, 1);
    gemm_out_kernel<<<gg, 512, 0, stream>>>(attb, Wto, bo, (float*)d_out, M);
}